// Round 7
// baseline (206.511 us; speedup 1.0000x reference)
//
#include <hip/hip_runtime.h>
#include <math.h>

// Problem constants
#define B_ 64
#define N_ 128
#define D_ 128
#define BN_ 8192
#define NG_ 50
#define CUTOFF_ 10.0f

typedef __attribute__((ext_vector_type(8))) short short8v;   // 8 bf16
typedef __attribute__((ext_vector_type(4))) float f32x4;
#define MFMA16 __builtin_amdgcn_mfma_f32_16x16x32_bf16

__device__ __forceinline__ float bf2f(unsigned short h) {
    return __builtin_bit_cast(float, ((unsigned int)h) << 16);
}
__device__ __forceinline__ unsigned short f2bf(float f) {
    unsigned int u = __builtin_bit_cast(unsigned int, f);
    return (unsigned short)((u + 0x7FFFu + ((u >> 16) & 1u)) >> 16);
}
__device__ __forceinline__ void splitbf(float x, unsigned short& h, unsigned short& l) {
    h = f2bf(x);
    l = f2bf(x - bf2f(h));
}
__device__ __forceinline__ void gl_lds(const void* g, void* l) {
    __builtin_amdgcn_global_load_lds(
        (const __attribute__((address_space(1))) void*)g,
        (__attribute__((address_space(3))) void*)l, 16, 0, 0);
}

// ---------------------------------------------------------------------------
// prep_k: weight transposes / fusions + passthrough copy.  grid 642 x 256
__global__ __launch_bounds__(256) void prep_k(
        const float* __restrict__ w1, const float* __restrict__ w2,
        const float* __restrict__ b2, const float* __restrict__ in_proj,
        const float* __restrict__ xpw, const float* __restrict__ dtw,
        const float* __restrict__ out_proj, const float* __restrict__ conv_w,
        const float* __restrict__ pos, const int* __restrict__ mi,
        unsigned short* __restrict__ w1Th, unsigned short* __restrict__ w1Tl,
        unsigned short* __restrict__ WdTh, unsigned short* __restrict__ WdTl,
        unsigned short* __restrict__ opTh, unsigned short* __restrict__ opTl,
        unsigned short* __restrict__ WfTh, unsigned short* __restrict__ WfTl,
        float* __restrict__ bfv, float* __restrict__ cwT,
        float* __restrict__ xpw8T, float* __restrict__ out) {
    int blk = blockIdx.x, t = threadIdx.x;
    if (blk < 128) {                       // w1T[n=t][k=blk]
        if (t < 128) {
            unsigned short h, l;
            splitbf(w1[blk * 128 + t], h, l);
            w1Th[t * 128 + blk] = h; w1Tl[t * 128 + blk] = l;
        }
    } else if (blk < 256) {                // WdT[n=t][k=m]
        int m = blk - 128;
        if (t < 128) {
            float s = 0.0f;
            #pragma unroll
            for (int r = 0; r < 8; r++) s = fmaf(xpw[m * 12 + r], dtw[r * 128 + t], s);
            unsigned short h, l; splitbf(s, h, l);
            WdTh[t * 128 + m] = h; WdTl[t * 128 + m] = l;
        }
    } else if (blk < 384) {                // opT[n=t][k]
        int k = blk - 256;
        if (t < 128) {
            unsigned short h, l;
            splitbf(out_proj[k * 128 + t], h, l);
            opTh[t * 128 + k] = h; opTl[t * 128 + k] = l;
        }
    } else if (blk < 512) {                // WfT[n=t(0..255)][k]
        int k = blk - 384;
        float s = 0.0f;
        #pragma unroll 8
        for (int j = 0; j < 128; j++) s = fmaf(w2[k * 128 + j], in_proj[j * 256 + t], s);
        unsigned short h, l; splitbf(s, h, l);
        WfTh[t * 128 + k] = h; WfTl[t * 128 + k] = l;
    } else if (blk == 512) {               // bfv = b2 @ in_proj
        float s = 0.0f;
        #pragma unroll 8
        for (int j = 0; j < 128; j++) s = fmaf(b2[j], in_proj[j * 256 + t], s);
        bfv[t] = s;
    } else if (blk < 641) {                // passthrough copy
        int idx = (blk - 513) * 256 + t;
        if (idx < BN_ * 3) out[(size_t)BN_ * D_ + idx] = pos[idx];
        if (idx < BN_) out[(size_t)BN_ * D_ + BN_ * 3 + idx] = (float)mi[idx];
    } else {                               // conv/xpw transposes
        if (t < 128) {
            #pragma unroll
            for (int jj = 0; jj < 4; jj++) cwT[jj * 128 + t] = conv_w[t * 4 + jj];
            #pragma unroll
            for (int c = 0; c < 4; c++) xpw8T[c * 128 + t] = xpw[t * 12 + 8 + c];
        }
    }
}

// ---------------------------------------------------------------------------
// fragment-GEMM helpers (128x128 tile, 8 waves as 2x4, verified layout)
template <int TERMS>   // 1: Ah*B ; 3: (Ah+Al)*B
__device__ __forceinline__ void gemm_pass(const char* sm, int ah, int al, int bo,
                                          int wm, int wn, int rlow, int khi,
                                          f32x4 (&acc)[4][2]) {
    #pragma unroll
    for (int kb = 0; kb < 4; kb++) {
        int kbyte = kb * 64 + khi;
        #pragma unroll
        for (int cf = 0; cf < 2; cf++) {
            int nB = wn * 32 + cf * 16 + rlow;
            short8v bf = *(const short8v*)(sm + bo + nB * 256 + (kbyte ^ ((nB & 7) << 4)));
            #pragma unroll
            for (int rf = 0; rf < 4; rf++) {
                int ra = wm * 64 + rf * 16 + rlow;
                int ao = ra * 256 + (kbyte ^ ((ra & 7) << 4));
                if (TERMS & 1) {
                    short8v av = *(const short8v*)(sm + ah + ao);
                    acc[rf][cf] = MFMA16(av, bf, acc[rf][cf], 0, 0, 0);
                }
                if (TERMS & 2) {
                    short8v av = *(const short8v*)(sm + al + ao);
                    acc[rf][cf] = MFMA16(av, bf, acc[rf][cf], 0, 0, 0);
                }
            }
        }
    }
}
// async DMA staging (cross-dispatch weight planes only — proven path)
__device__ __forceinline__ void stage_pl(char* dst, const unsigned short* g, int tid) {
    #pragma unroll
    for (int i = 0; i < 4; i++) {
        int s = tid + i * 512;
        int row = s >> 4, inner = s & 15;
        int gb = (inner * 16) ^ ((row & 7) << 4);
        gl_lds((const char*)g + row * 256 + gb, dst + s * 16);
    }
}
// reg-staged staging for buffers written earlier in THIS kernel (safe
// visibility: normal load -> swizzled ds_write; barrier = block fence)
__device__ __forceinline__ void stage_reg(char* dst, const unsigned short* g, int tid) {
    #pragma unroll
    for (int i = 0; i < 4; i++) {
        int s = tid + i * 512;
        int row = s >> 4, inner = s & 15;
        short8v v = *(const short8v*)((const char*)g + row * 256 + inner * 16);
        *(short8v*)(dst + row * 256 + ((inner * 16) ^ ((row & 7) << 4))) = v;
    }
}
__device__ __forceinline__ void zacc(f32x4 (&a)[4][2]) {
    #pragma unroll
    for (int i = 0; i < 4; i++) {
        a[i][0] = (f32x4){0.f, 0.f, 0.f, 0.f};
        a[i][1] = (f32x4){0.f, 0.f, 0.f, 0.f};
    }
}

// ---------------------------------------------------------------------------
// batch_k: one block per batch, the whole pipeline.  grid 64 x 512
__global__ __launch_bounds__(512, 2) void batch_k(
        const float* __restrict__ x, const float* __restrict__ norm_w,
        const float* __restrict__ pos,
        const float* __restrict__ lin_w, const float* __restrict__ lin_b,
        const float* __restrict__ b1, const float* __restrict__ dtb,
        const float* __restrict__ conv_b,
        const float* __restrict__ cwT, const float* __restrict__ xpw8T,
        const float* __restrict__ A_log, const float* __restrict__ Dpar,
        const unsigned short* __restrict__ w1Th, const unsigned short* __restrict__ w1Tl,
        const unsigned short* __restrict__ WdTh, const unsigned short* __restrict__ WdTl,
        const unsigned short* __restrict__ opTh, const unsigned short* __restrict__ opTl,
        const unsigned short* __restrict__ WfTh, const unsigned short* __restrict__ WfTl,
        const float* __restrict__ bfv,
        unsigned short* __restrict__ adjh, unsigned short* __restrict__ adjl,
        unsigned short* __restrict__ emb, float* __restrict__ rdegbuf,
        float* __restrict__ x1f, float* __restrict__ resbuf,
        float* __restrict__ bcbuf, unsigned short* __restrict__ ylobuf,
        float* __restrict__ out) {
    __shared__ __align__(16) char sm[163840];
    const int SA = 0, SAL = 32768, SX = 65536, SXL = 98304, BS = 131072;
    int b = blockIdx.x;
    int tid = threadIdx.x;
    int w = tid >> 6, l = tid & 63;
    int wm = w >> 2, wn = w & 3;
    int rlow = l & 15, khi = (l >> 4) * 16, qrow = (l >> 4) * 4;
    f32x4 acc[4][2];

    // ---- P0: adjacency (adj/em planes, rdeg) for this batch
    if (tid < 384) ((float*)(sm + BS))[tid] = pos[(size_t)b * 384 + tid];
    else if (tid < 384 + NG_) ((float*)(sm + BS))[tid] = lin_w[tid - 384];
    __syncthreads();
    {
        const float* p3 = (const float*)(sm + BS);
        const float* lwp = p3 + 384;
        int i = tid >> 2, jg = tid & 3;
        float pix = p3[i * 3], piy = p3[i * 3 + 1], piz = p3[i * 3 + 2];
        const float DEL = 10.0f / 49.0f;
        const float COEFF = -0.5f / (DEL * DEL);
        float linb = lin_b[0];
        int cnt = 0;
        size_t rbase = ((size_t)b * N_ + i) * N_;
        for (int jj = 0; jj < 32; jj++) {
            int j = jg * 32 + jj;
            float dx = pix - p3[j * 3], dy = piy - p3[j * 3 + 1], dz = piz - p3[j * 3 + 2];
            float d2 = dx * dx + dy * dy + dz * dz;
            float dist = (i == j) ? 1.0f : sqrtf(d2);
            bool edge = (i != j) && (dist < CUTOFF_);
            float val = 0.0f;
            if (edge) {
                cnt++;
                int g0 = (int)ceilf((dist - 1.75f) / DEL); if (g0 < 0) g0 = 0;
                int g1 = (int)floorf((dist + 1.75f) / DEL); if (g1 > NG_ - 1) g1 = NG_ - 1;
                float s = linb;
                for (int g = g0; g <= g1; g++) {
                    float t = dist - (float)g * DEL;
                    s += lwp[g] * expf(COEFF * t * t);
                }
                val = s;
            }
            unsigned short hh, ll; splitbf(val, hh, ll);
            adjh[rbase + j] = hh; adjl[rbase + j] = ll;
            emb[rbase + j] = edge ? 0x3F80 : 0;
        }
        cnt += __shfl_xor(cnt, 1, 64);
        cnt += __shfl_xor(cnt, 2, 64);
        if (jg == 0) rdegbuf[b * N_ + i] = 1.0f / (float)(cnt > 0 ? cnt : 1);
    }
    __syncthreads();

    // ---- P1: RMSNorm -> x1f (global, exact) + x1 planes -> SA
    {
        int row = tid >> 2, q = tid & 3;
        size_t gb = (size_t)b * 16384 + (size_t)row * 128 + q * 32;
        float4 xa[8];
        float ss = 0.0f;
        #pragma unroll
        for (int k = 0; k < 8; k++) {
            xa[k] = *(const float4*)(x + gb + k * 4);
            ss += xa[k].x * xa[k].x + xa[k].y * xa[k].y + xa[k].z * xa[k].z + xa[k].w * xa[k].w;
        }
        ss += __shfl_xor(ss, 1, 64);
        ss += __shfl_xor(ss, 2, 64);
        float r = rsqrtf(ss * (1.0f / 128.0f) + 1e-5f);
        int Z = (row & 7) << 4;
        #pragma unroll
        for (int k = 0; k < 8; k++) {
            float4 wv = *(const float4*)(norm_w + q * 32 + k * 4);
            float o0 = xa[k].x * r * wv.x, o1 = xa[k].y * r * wv.y;
            float o2 = xa[k].z * r * wv.z, o3 = xa[k].w * r * wv.w;
            *(float4*)(x1f + gb + k * 4) = make_float4(o0, o1, o2, o3);
            unsigned short h0, l0, h1, l1, h2, l2, h3, l3;
            splitbf(o0, h0, l0); splitbf(o1, h1, l1);
            splitbf(o2, h2, l2); splitbf(o3, h3, l3);
            int byo = ((q * 32 + k * 4) * 2) ^ Z;
            *(ushort4*)(sm + SA + row * 256 + byo) = make_ushort4(h0, h1, h2, h3);
            *(ushort4*)(sm + SAL + row * 256 + byo) = make_ushort4(l0, l1, l2, l3);
        }
    }
    __syncthreads();

    // ---- P2: h = relu(x1 @ w1 + b1) -> hT planes in SX
    zacc(acc);
    stage_pl(sm + BS, w1Th, tid); __syncthreads();
    gemm_pass<3>(sm, SA, SAL, BS, wm, wn, rlow, khi, acc); __syncthreads();
    stage_pl(sm + BS, w1Tl, tid); __syncthreads();
    gemm_pass<1>(sm, SA, SAL, BS, wm, wn, rlow, khi, acc);
    #pragma unroll
    for (int rf = 0; rf < 4; rf++)
    #pragma unroll
    for (int cf = 0; cf < 2; cf++) {
        int colg = wn * 32 + cf * 16 + rlow;
        int row0 = wm * 64 + rf * 16 + qrow;
        float bb = b1[colg];
        unsigned short h4[4], l4[4];
        #pragma unroll
        for (int q = 0; q < 4; q++) {
            float t = fmaxf(acc[rf][cf][q] + bb, 0.0f);
            splitbf(t, h4[q], l4[q]);
        }
        int byo = (row0 * 2) ^ ((colg & 7) << 4);
        *(ushort4*)(sm + SX + colg * 256 + byo) = make_ushort4(h4[0], h4[1], h4[2], h4[3]);
        *(ushort4*)(sm + SXL + colg * 256 + byo) = make_ushort4(l4[0], l4[1], l4[2], l4[3]);
    }
    __syncthreads();

    // ---- P3: agg = (em @ h) * rdeg -> agg planes in SA
    stage_reg(sm + SA, emb + (size_t)b * 16384, tid); __syncthreads();
    zacc(acc);
    #pragma unroll
    for (int kb = 0; kb < 4; kb++) {
        int kbyte = kb * 64 + khi;
        #pragma unroll
        for (int cf = 0; cf < 2; cf++) {
            int nB = wn * 32 + cf * 16 + rlow;
            int boff = nB * 256 + (kbyte ^ ((nB & 7) << 4));
            short8v bh = *(const short8v*)(sm + SX + boff);
            short8v bl = *(const short8v*)(sm + SXL + boff);
            #pragma unroll
            for (int rf = 0; rf < 4; rf++) {
                int ra = wm * 64 + rf * 16 + rlow;
                short8v ah = *(const short8v*)(sm + SA + ra * 256 + (kbyte ^ ((ra & 7) << 4)));
                acc[rf][cf] = MFMA16(ah, bh, acc[rf][cf], 0, 0, 0);
                acc[rf][cf] = MFMA16(ah, bl, acc[rf][cf], 0, 0, 0);
            }
        }
    }
    __syncthreads();
    #pragma unroll
    for (int rf = 0; rf < 4; rf++)
    #pragma unroll
    for (int cf = 0; cf < 2; cf++) {
        int colg = wn * 32 + cf * 16 + rlow;
        int row0 = wm * 64 + rf * 16 + qrow;
        #pragma unroll
        for (int q = 0; q < 4; q++) {
            int row = row0 + q;
            float t = acc[rf][cf][q] * rdegbuf[b * 128 + row];
            unsigned short hh, ll; splitbf(t, hh, ll);
            int byo = (colg * 2) ^ ((row & 7) << 4);
            *(unsigned short*)(sm + SA + row * 256 + byo) = hh;
            *(unsigned short*)(sm + SAL + row * 256 + byo) = ll;
        }
    }
    __syncthreads();

    // ---- P4: xr = agg @ Wf + bf ; xm -> SA (f32 swz), silu(res) -> global
    {
        f32x4 acc2[4][2];
        zacc(acc); zacc(acc2);
        stage_pl(sm + BS, WfTh, tid); __syncthreads();
        gemm_pass<3>(sm, SA, SAL, BS, wm, wn, rlow, khi, acc); __syncthreads();
        stage_pl(sm + BS, WfTl, tid); __syncthreads();
        gemm_pass<1>(sm, SA, SAL, BS, wm, wn, rlow, khi, acc); __syncthreads();
        stage_pl(sm + BS, WfTh + 16384, tid); __syncthreads();   // rows n=128..255
        gemm_pass<3>(sm, SA, SAL, BS, wm, wn, rlow, khi, acc2); __syncthreads();
        stage_pl(sm + BS, WfTl + 16384, tid); __syncthreads();   // rows n=128..255
        gemm_pass<1>(sm, SA, SAL, BS, wm, wn, rlow, khi, acc2);
        __syncthreads();   // all agg-plane reads done
        #pragma unroll
        for (int rf = 0; rf < 4; rf++)
        #pragma unroll
        for (int cf = 0; cf < 2; cf++) {
            int colg = wn * 32 + cf * 16 + rlow;
            int row0 = wm * 64 + rf * 16 + qrow;
            float bb0 = bfv[colg], bb1 = bfv[128 + colg];
            #pragma unroll
            for (int q = 0; q < 4; q++) {
                int row = row0 + q;
                float xm = acc[rf][cf][q] + bb0;
                *(float*)(sm + row * 512 + ((colg * 4) ^ ((row & 7) << 4))) = xm;
                float rs = acc2[rf][cf][q] + bb1;
                rs = rs / (1.0f + expf(-rs));
                resbuf[(size_t)b * 16384 + row * 128 + colg] = rs;
            }
        }
    }
    __syncthreads();

    // ---- P5: conv1d + silu -> xc planes in SA ; bc -> global
    {
        int tt0 = tid >> 2, dg = tid & 3, d0 = dg * 32;
        float xcr[32];
        float p0 = 0, p1 = 0, p2 = 0, p3 = 0;
        #pragma unroll
        for (int k = 0; k < 8; k++) {
            int dbase = d0 + k * 4;
            float4 a4 = *(const float4*)(conv_b + dbase);
            float av0 = a4.x, av1 = a4.y, av2 = a4.z, av3 = a4.w;
            #pragma unroll
            for (int jj = 0; jj < 4; jj++) {
                int tt = tt0 + jj - 3;
                if (tt >= 0) {
                    f32x4 xv = *(const f32x4*)(sm + tt * 512 + ((dbase * 4) ^ ((tt & 7) << 4)));
                    float4 cw4 = *(const float4*)(cwT + jj * 128 + dbase);
                    av0 = fmaf(xv[0], cw4.x, av0);
                    av1 = fmaf(xv[1], cw4.y, av1);
                    av2 = fmaf(xv[2], cw4.z, av2);
                    av3 = fmaf(xv[3], cw4.w, av3);
                }
            }
            float c0 = av0 / (1.0f + expf(-av0));
            float c1 = av1 / (1.0f + expf(-av1));
            float c2 = av2 / (1.0f + expf(-av2));
            float c3 = av3 / (1.0f + expf(-av3));
            xcr[k * 4] = c0; xcr[k * 4 + 1] = c1; xcr[k * 4 + 2] = c2; xcr[k * 4 + 3] = c3;
            float4 w0 = *(const float4*)(xpw8T + 0 * 128 + dbase);
            float4 w1v = *(const float4*)(xpw8T + 1 * 128 + dbase);
            float4 w2v = *(const float4*)(xpw8T + 2 * 128 + dbase);
            float4 w3v = *(const float4*)(xpw8T + 3 * 128 + dbase);
            p0 += c0 * w0.x + c1 * w0.y + c2 * w0.z + c3 * w0.w;
            p1 += c0 * w1v.x + c1 * w1v.y + c2 * w1v.z + c3 * w1v.w;
            p2 += c0 * w2v.x + c1 * w2v.y + c2 * w2v.z + c3 * w2v.w;
            p3 += c0 * w3v.x + c1 * w3v.y + c2 * w3v.z + c3 * w3v.w;
        }
        p0 += __shfl_xor(p0, 1, 64); p0 += __shfl_xor(p0, 2, 64);
        p1 += __shfl_xor(p1, 1, 64); p1 += __shfl_xor(p1, 2, 64);
        p2 += __shfl_xor(p2, 1, 64); p2 += __shfl_xor(p2, 2, 64);
        p3 += __shfl_xor(p3, 1, 64); p3 += __shfl_xor(p3, 2, 64);
        float pv = (dg == 0) ? p0 : (dg == 1) ? p1 : (dg == 2) ? p2 : p3;
        bcbuf[((size_t)b * 128 + tt0) * 4 + dg] = pv;
        __syncthreads();   // all xm reads done
        int Zt = (tt0 & 7) << 4;
        #pragma unroll
        for (int k = 0; k < 8; k++) {
            int dbase = d0 + k * 4;
            unsigned short h0, l0, h1, l1, h2, l2, h3, l3;
            splitbf(xcr[k * 4], h0, l0); splitbf(xcr[k * 4 + 1], h1, l1);
            splitbf(xcr[k * 4 + 2], h2, l2); splitbf(xcr[k * 4 + 3], h3, l3);
            int byo = (dbase * 2) ^ Zt;
            *(ushort4*)(sm + SA + tt0 * 256 + byo) = make_ushort4(h0, h1, h2, h3);
            *(ushort4*)(sm + SAL + tt0 * 256 + byo) = make_ushort4(l0, l1, l2, l3);
        }
    }
    __syncthreads();

    // ---- P6: delta = softplus(xc @ Wd + dtb) -> delta planes in SX
    zacc(acc);
    stage_pl(sm + BS, WdTh, tid); __syncthreads();
    gemm_pass<3>(sm, SA, SAL, BS, wm, wn, rlow, khi, acc); __syncthreads();
    stage_pl(sm + BS, WdTl, tid); __syncthreads();
    gemm_pass<1>(sm, SA, SAL, BS, wm, wn, rlow, khi, acc);
    #pragma unroll
    for (int rf = 0; rf < 4; rf++)
    #pragma unroll
    for (int cf = 0; cf < 2; cf++) {
        int colg = wn * 32 + cf * 16 + rlow;
        int row0 = wm * 64 + rf * 16 + qrow;
        float db = dtb[colg];
        #pragma unroll
        for (int q = 0; q < 4; q++) {
            int row = row0 + q;
            float t = acc[rf][cf][q] + db;
            t = fmaxf(t, 0.0f) + log1pf(expf(-fabsf(t)));
            unsigned short hh, ll; splitbf(t, hh, ll);
            int byo = (colg * 2) ^ ((row & 7) << 4);
            *(unsigned short*)(sm + SX + row * 256 + byo) = hh;
            *(unsigned short*)(sm + SXL + row * 256 + byo) = ll;
        }
    }
    __syncthreads();

    // ---- P7: dp = delta @ adj  -> SX region as f32 [t][128]
    zacc(acc);
    stage_reg(sm + BS, adjh + (size_t)b * 16384, tid); __syncthreads();
    gemm_pass<3>(sm, SX, SXL, BS, wm, wn, rlow, khi, acc); __syncthreads();
    stage_reg(sm + BS, adjl + (size_t)b * 16384, tid); __syncthreads();
    gemm_pass<1>(sm, SX, SXL, BS, wm, wn, rlow, khi, acc);
    __syncthreads();   // delta-plane reads done
    #pragma unroll
    for (int rf = 0; rf < 4; rf++)
    #pragma unroll
    for (int cf = 0; cf < 2; cf++) {
        int colg = wn * 32 + cf * 16 + rlow;
        int row0 = wm * 64 + rf * 16 + qrow;
        #pragma unroll
        for (int q = 0; q < 4; q++)
            *(float*)(sm + SX + (row0 + q) * 512 + colg * 4) = acc[rf][cf][q];
    }
    __syncthreads();

    // ---- P8: selective scan -> y-hi in BS (LDS), y-lo -> global
    if (tid < 256) {
        int d = tid >> 1, s = tid & 1;
        float a = -expf(A_log[d * 2 + s]);
        float Dp = Dpar[d];
        float h = 0.0f;
        size_t bg = (size_t)b * 16384;
        const float* bcb = bcbuf + (size_t)b * 512;
        int Zd2 = d * 2;
        for (int t = 0; t < 128; t++) {
            float dpv = *(const float*)(sm + SX + t * 512 + d * 4);
            int Zt = (t & 7) << 4;
            float xcv = bf2f(*(const unsigned short*)(sm + SA + t * 256 + (Zd2 ^ Zt)))
                      + bf2f(*(const unsigned short*)(sm + SAL + t * 256 + (Zd2 ^ Zt)));
            float bm = bcb[t * 4 + s];
            float cm = bcb[t * 4 + 2 + s];
            float e = expf(dpv * a);
            h = fmaf(e, h, dpv * xcv * bm);
            float yc = h * cm;
            float ysum = yc + __shfl_xor(yc, 1, 64);
            if (s == 0) {
                float yv = fmaf(xcv, Dp, ysum) * resbuf[bg + t * 128 + d];
                unsigned short hh, ll; splitbf(yv, hh, ll);
                *(unsigned short*)(sm + BS + t * 256 + (Zd2 ^ Zt)) = hh;
                ylobuf[bg + t * 128 + d] = ll;
            }
        }
    }
    __syncthreads();

    // ---- P9: out = clean(y @ out_proj) + x1
    stage_reg(sm + SA, ylobuf + (size_t)b * 16384, tid);   // y-lo -> SA
    stage_pl(sm + SX, opTh, tid);
    __syncthreads();
    zacc(acc);
    gemm_pass<3>(sm, BS, SA, SX, wm, wn, rlow, khi, acc); __syncthreads();
    stage_pl(sm + SX, opTl, tid); __syncthreads();
    gemm_pass<1>(sm, BS, SA, SX, wm, wn, rlow, khi, acc);
    #pragma unroll
    for (int rf = 0; rf < 4; rf++)
    #pragma unroll
    for (int cf = 0; cf < 2; cf++) {
        int colg = wn * 32 + cf * 16 + rlow;
        int row0 = wm * 64 + rf * 16 + qrow;
        #pragma unroll
        for (int q = 0; q < 4; q++) {
            int row = row0 + q;
            float t = acc[rf][cf][q];
            t = isfinite(t) ? t : 0.0f;
            size_t g = (size_t)b * 16384 + (size_t)row * 128 + colg;
            out[g] = t + x1f[g];
        }
    }
}

// ---------------------------------------------------------------------------
extern "C" void kernel_launch(void* const* d_in, const int* in_sizes, int n_in,
                              void* d_out, int out_size, void* d_ws, size_t ws_size,
                              hipStream_t stream) {
    const float* x        = (const float*)d_in[0];
    const float* pos      = (const float*)d_in[1];
    const int*   mi       = (const int*)d_in[2];
    const float* norm_w   = (const float*)d_in[4];
    const float* w1       = (const float*)d_in[5];
    const float* b1       = (const float*)d_in[6];
    const float* w2       = (const float*)d_in[7];
    const float* b2       = (const float*)d_in[8];
    const float* lin_w    = (const float*)d_in[9];
    const float* lin_b    = (const float*)d_in[10];
    const float* in_proj  = (const float*)d_in[11];
    const float* conv_w   = (const float*)d_in[12];
    const float* conv_b   = (const float*)d_in[13];
    const float* xpw      = (const float*)d_in[14];
    const float* dtw      = (const float*)d_in[15];
    const float* dtb      = (const float*)d_in[16];
    const float* A_log    = (const float*)d_in[17];
    const float* Dpar     = (const float*)d_in[18];
    const float* out_proj = (const float*)d_in[19];

    float* out = (float*)d_out;
    char* base = (char*)d_ws;
    const size_t MB = 1u << 20;

    float* x1f    = (float*)(base);                         // 4 MB
    float* resbuf = (float*)(base + 4 * MB);                // 4 MB
    float* bcbuf  = (float*)(base + 8 * MB);                // 128 KB
    float* rdeg   = (float*)(base + 8 * MB + 131072);       // 32 KB
    float* cwT    = (float*)(base + 8 * MB + 163840);       // 2 KB
    float* xpw8T  = (float*)(base + 8 * MB + 165888);       // 2 KB
    float* bfv    = (float*)(base + 8 * MB + 167936);       // 1 KB
    unsigned short* adjh   = (unsigned short*)(base + 9 * MB);    // 2 MB
    unsigned short* adjl   = (unsigned short*)(base + 11 * MB);   // 2 MB
    unsigned short* emb    = (unsigned short*)(base + 13 * MB);   // 2 MB
    unsigned short* ylobuf = (unsigned short*)(base + 15 * MB);   // 2 MB
    unsigned short* w1Th   = (unsigned short*)(base + 17 * MB);
    unsigned short* w1Tl   = w1Th + 16384;
    unsigned short* WdTh   = w1Th + 2 * 16384;
    unsigned short* WdTl   = w1Th + 3 * 16384;
    unsigned short* opTh   = w1Th + 4 * 16384;
    unsigned short* opTl   = w1Th + 5 * 16384;
    unsigned short* WfTh   = w1Th + 6 * 16384;              // [256][128] = 32768 elems
    unsigned short* WfTl   = WfTh + 32768;

    prep_k<<<642, 256, 0, stream>>>(w1, w2, b2, in_proj, xpw, dtw, out_proj, conv_w,
                                    pos, mi, w1Th, w1Tl, WdTh, WdTl, opTh, opTl,
                                    WfTh, WfTl, bfv, cwT, xpw8T, out);
    batch_k<<<B_, 512, 0, stream>>>(x, norm_w, pos, lin_w, lin_b, b1, dtb, conv_b,
                                    cwT, xpw8T, A_log, Dpar,
                                    w1Th, w1Tl, WdTh, WdTl, opTh, opTl, WfTh, WfTl,
                                    bfv, adjh, adjl, emb, rdeg,
                                    x1f, resbuf, bcbuf, ylobuf, out);
}

// Round 8
// 95.705 us; speedup vs baseline: 2.1578x; 2.1578x over previous
//
#include <hip/hip_runtime.h>
#include <math.h>

// Problem constants
#define B_ 64
#define N_ 128
#define D_ 128
#define BN_ 8192
#define NG_ 50
#define CUTOFF_ 10.0f

typedef __attribute__((ext_vector_type(8))) short short8v;   // 8 bf16
typedef __attribute__((ext_vector_type(4))) float f32x4;
#define MFMA16 __builtin_amdgcn_mfma_f32_16x16x32_bf16

__device__ __forceinline__ float bf2f(unsigned short h) {
    return __builtin_bit_cast(float, ((unsigned int)h) << 16);
}
__device__ __forceinline__ unsigned short f2bf(float f) {
    unsigned int u = __builtin_bit_cast(unsigned int, f);
    return (unsigned short)((u + 0x7FFFu + ((u >> 16) & 1u)) >> 16);
}
__device__ __forceinline__ void splitbf(float x, unsigned short& h, unsigned short& l) {
    h = f2bf(x);
    l = f2bf(x - bf2f(h));
}
__device__ __forceinline__ void gl_lds(const void* g, void* l) {
    __builtin_amdgcn_global_load_lds(
        (const __attribute__((address_space(1))) void*)g,
        (__attribute__((address_space(3))) void*)l, 16, 0, 0);
}

// ---------------------------------------------------------------------------
// setup_k: weight prep [0,513) | passthrough copy [513,642) | RMSNorm [642,2690)
//          | adjacency [2690,3714).  All sections independent; full-chip grid.
__global__ __launch_bounds__(256) void setup_k(
        const float* __restrict__ x, const float* __restrict__ norm_w,
        const float* __restrict__ pos, const int* __restrict__ mi,
        const float* __restrict__ lin_w, const float* __restrict__ lin_b,
        const float* __restrict__ w1, const float* __restrict__ w2,
        const float* __restrict__ b2, const float* __restrict__ in_proj,
        const float* __restrict__ xpw, const float* __restrict__ dtw,
        const float* __restrict__ out_proj,
        unsigned short* __restrict__ w1Th, unsigned short* __restrict__ w1Tl,
        unsigned short* __restrict__ WdTh, unsigned short* __restrict__ WdTl,
        unsigned short* __restrict__ opTh, unsigned short* __restrict__ opTl,
        unsigned short* __restrict__ WfTh, unsigned short* __restrict__ WfTl,
        float* __restrict__ bfv,
        float* __restrict__ x1f, unsigned short* __restrict__ x1h,
        unsigned short* __restrict__ x1l,
        unsigned short* __restrict__ adjh, unsigned short* __restrict__ adjl,
        unsigned short* __restrict__ emh, float* __restrict__ rdeg,
        float* __restrict__ out) {
    int blk = blockIdx.x, t = threadIdx.x;
    if (blk < 513) {
        // ---- weight prep (round-5 proven) ----
        if (blk < 128) {
            if (t < 128) {
                unsigned short h, l;
                splitbf(w1[blk * 128 + t], h, l);
                w1Th[t * 128 + blk] = h; w1Tl[t * 128 + blk] = l;
            }
        } else if (blk < 256) {
            int m = blk - 128;
            if (t < 128) {
                float s = 0.0f;
                #pragma unroll
                for (int r = 0; r < 8; r++) s = fmaf(xpw[m * 12 + r], dtw[r * 128 + t], s);
                unsigned short h, l; splitbf(s, h, l);
                WdTh[t * 128 + m] = h; WdTl[t * 128 + m] = l;
            }
        } else if (blk < 384) {
            int k = blk - 256;
            if (t < 128) {
                unsigned short h, l;
                splitbf(out_proj[k * 128 + t], h, l);
                opTh[t * 128 + k] = h; opTl[t * 128 + k] = l;
            }
        } else if (blk < 512) {
            int k = blk - 384;
            float s = 0.0f;
            #pragma unroll 8
            for (int j = 0; j < 128; j++) s = fmaf(w2[k * 128 + j], in_proj[j * 256 + t], s);
            unsigned short h, l; splitbf(s, h, l);
            WfTh[t * 128 + k] = h; WfTl[t * 128 + k] = l;
        } else {
            float s = 0.0f;
            #pragma unroll 8
            for (int j = 0; j < 128; j++) s = fmaf(b2[j], in_proj[j * 256 + t], s);
            bfv[t] = s;
        }
    } else if (blk < 642) {
        // ---- passthrough copy ----
        int idx = (blk - 513) * 256 + t;
        if (idx < BN_ * 3) out[(size_t)BN_ * D_ + idx] = pos[idx];
        if (idx < BN_) out[(size_t)BN_ * D_ + BN_ * 3 + idx] = (float)mi[idx];
    } else if (blk < 2690) {
        // ---- RMSNorm (wave-per-row, 4 rows/block), round-5 proven ----
        int rblk = blk - 642;
        int wv = t >> 6, ln = t & 63;
        int row = rblk * 4 + wv;
        const float2* xr = reinterpret_cast<const float2*>(x) + (size_t)row * 64;
        float2 v = xr[ln];
        float s = fmaf(v.x, v.x, v.y * v.y);
        #pragma unroll
        for (int o = 32; o > 0; o >>= 1) s += __shfl_down(s, o, 64);
        float tot = __shfl(s, 0, 64);
        float r = rsqrtf(tot * (1.0f / D_) + 1e-5f);
        float2 wv2 = reinterpret_cast<const float2*>(norm_w)[ln];
        float o0 = v.x * r * wv2.x, o1 = v.y * r * wv2.y;
        reinterpret_cast<float2*>(x1f)[(size_t)row * 64 + ln] = make_float2(o0, o1);
        unsigned short h0, l0, h1, l1;
        splitbf(o0, h0, l0); splitbf(o1, h1, l1);
        reinterpret_cast<ushort2*>(x1h)[(size_t)row * 64 + ln] = make_ushort2(h0, h1);
        reinterpret_cast<ushort2*>(x1l)[(size_t)row * 64 + ln] = make_ushort2(l0, l1);
    } else {
        // ---- adjacency (round-5 proven, linearized block index) ----
        __shared__ float px[N_], py[N_], pz[N_];
        __shared__ float lw[NG_];
        __shared__ int degs[8];
        int ablk = blk - 2690;
        int bx = ablk & 15, b = ablk >> 4;
        if (t < N_) {
            const float* p = pos + (size_t)(b * N_ + t) * 3;
            px[t] = p[0]; py[t] = p[1]; pz[t] = p[2];
        } else if (t - N_ < NG_) {
            lw[t - N_] = lin_w[t - N_];
        }
        if (t >= 248) degs[t - 248] = 0;
        __syncthreads();
        float linb = lin_b[0];
        int j = t & 127;
        int il = t >> 7;
        const float DEL = 10.0f / 49.0f;
        const float COEFF = -0.5f / (DEL * DEL);
        #pragma unroll
        for (int p = 0; p < 4; p++) {
            int i = bx * 8 + p * 2 + il;
            float dx = px[i] - px[j], dy = py[i] - py[j], dz = pz[i] - pz[j];
            float d2 = dx * dx + dy * dy + dz * dz;
            float dist = (i == j) ? 1.0f : sqrtf(d2);
            bool edge = (i != j) && (dist < CUTOFF_);
            float val = 0.0f;
            if (edge) {
                int g0 = (int)ceilf((dist - 1.75f) / DEL); if (g0 < 0) g0 = 0;
                int g1 = (int)floorf((dist + 1.75f) / DEL); if (g1 > NG_ - 1) g1 = NG_ - 1;
                float s = linb;
                for (int g = g0; g <= g1; g++) {
                    float tt = dist - (float)g * DEL;
                    s += lw[g] * expf(COEFF * tt * tt);
                }
                val = s;
            }
            size_t idx = ((size_t)b * N_ + i) * N_ + j;
            unsigned short h, l; splitbf(val, h, l);
            adjh[idx] = h; adjl[idx] = l;
            emh[idx] = edge ? 0x3F80 : 0;
            unsigned long long msk = __ballot(edge);
            if ((t & 63) == 0) atomicAdd(&degs[p * 2 + il], __popcll(msk));
        }
        __syncthreads();
        if (t < 8) {
            int dg = degs[t];
            rdeg[(size_t)b * N_ + bx * 8 + t] = 1.0f / (float)(dg > 0 ? dg : 1);
        }
    }
}

// ---------------------------------------------------------------------------
// Split-bf16 MFMA GEMM (round-5 proven core).  Block tile 32 rows x 64 cols,
// 4 waves, 48KB LDS, XOR-swizzled, global_load_lds staging.
// EPI: 1 relu+bias -> hT planes (batched) | 2 *AUX[row] -> planes |
//      4 softplus(+bias) -> planes | 5 isfinite + AUX residual -> fp32 |
//      6 split: col<128 -> Cf=xm fp32 (+bias); col>=128 -> Cf2=resT silu, [b][d][t] |
//      7 transposed fp32 store Cf=dpT [b][d][t]
#define AHOFF 0
#define ALOFF 8192
#define BHOFF 16384
#define BLOFF 32768
template <int EPI, bool ALO>
__global__ __launch_bounds__(256, 3) void mgemm_k(
        const unsigned short* __restrict__ Ah, const unsigned short* __restrict__ Al,
        const unsigned short* __restrict__ BTh, const unsigned short* __restrict__ BTl,
        const float* __restrict__ bias, const float* __restrict__ AUX,
        float* __restrict__ Cf, unsigned short* __restrict__ Ch,
        unsigned short* __restrict__ Cl, float* __restrict__ Cf2,
        int cstride, int wbs) {
    extern __shared__ char sm[];
    int tid = threadIdx.x;
    int row_base = blockIdx.x * 32;
    int col_base = blockIdx.y * 64;

    const unsigned short* pBh = BTh;
    const unsigned short* pBl = BTl;
    if (wbs) {
        size_t bo = (size_t)(row_base >> 7) * (size_t)wbs;
        pBh += bo; pBl += bo;
    }

    #pragma unroll
    for (int i = 0; i < 2; i++) {
        int s = tid + i * 256;
        int row = s >> 4, inner = s & 15;
        int gb = (inner * 16) ^ ((row & 7) << 4);
        size_t gsrc = (size_t)(row_base + row) * 256 + gb;
        gl_lds((const char*)Ah + gsrc, sm + AHOFF + s * 16);
        if (ALO) gl_lds((const char*)Al + gsrc, sm + ALOFF + s * 16);
    }
    #pragma unroll
    for (int i = 0; i < 4; i++) {
        int s = tid + i * 256;
        int n = s >> 4, inner = s & 15;
        int gb = (inner * 16) ^ ((n & 7) << 4);
        size_t gsrc = (size_t)(col_base + n) * 256 + gb;
        gl_lds((const char*)pBh + gsrc, sm + BHOFF + s * 16);
        gl_lds((const char*)pBl + gsrc, sm + BLOFF + s * 16);
    }
    __syncthreads();

    int w = tid >> 6, l = tid & 63;
    int rlow = l & 15, kb_lane = (l >> 4) * 16;
    int nB = w * 16 + rlow;
    int nswz = (nB & 7) << 4;
    f32x4 acc[2] = {{0.f, 0.f, 0.f, 0.f}, {0.f, 0.f, 0.f, 0.f}};
    #pragma unroll
    for (int kb = 0; kb < 4; kb++) {
        int kbyte = kb * 64 + kb_lane;
        short8v bh = *(const short8v*)(sm + BHOFF + nB * 256 + (kbyte ^ nswz));
        short8v bl = *(const short8v*)(sm + BLOFF + nB * 256 + (kbyte ^ nswz));
        #pragma unroll
        for (int rf = 0; rf < 2; rf++) {
            int ra = rf * 16 + rlow;
            int aswz = (ra & 7) << 4;
            short8v ah = *(const short8v*)(sm + AHOFF + ra * 256 + (kbyte ^ aswz));
            acc[rf] = MFMA16(ah, bh, acc[rf], 0, 0, 0);
            acc[rf] = MFMA16(ah, bl, acc[rf], 0, 0, 0);
            if (ALO) {
                short8v al_ = *(const short8v*)(sm + ALOFF + ra * 256 + (kbyte ^ aswz));
                acc[rf] = MFMA16(al_, bh, acc[rf], 0, 0, 0);
            }
        }
    }

    int colg = col_base + w * 16 + rlow;
    #pragma unroll
    for (int rf = 0; rf < 2; rf++) {
        int row0 = row_base + rf * 16 + (l >> 4) * 4;
        if (EPI == 1) {
            float b_ = bias[colg];
            unsigned short hh[4], ll[4];
            #pragma unroll
            for (int q = 0; q < 4; q++) {
                float t = fmaxf(acc[rf][q] + b_, 0.0f);
                splitbf(t, hh[q], ll[q]);
            }
            size_t bb = (size_t)(row0 >> 7) * 16384 + (size_t)colg * 128 + (row0 & 127);
            *reinterpret_cast<ushort4*>(Ch + bb) = make_ushort4(hh[0], hh[1], hh[2], hh[3]);
            *reinterpret_cast<ushort4*>(Cl + bb) = make_ushort4(ll[0], ll[1], ll[2], ll[3]);
        } else if (EPI == 7) {
            size_t bb = ((size_t)(row0 >> 7) * 128 + colg) * 128 + (row0 & 127);
            *reinterpret_cast<float4*>(Cf + bb) =
                make_float4(acc[rf][0], acc[rf][1], acc[rf][2], acc[rf][3]);
        } else if (EPI == 6 && colg >= 128) {
            float b_ = bias[colg];
            float v[4];
            #pragma unroll
            for (int q = 0; q < 4; q++) {
                float rs = acc[rf][q] + b_;
                v[q] = rs / (1.0f + expf(-rs));
            }
            size_t bb = ((size_t)(row0 >> 7) * 128 + (colg - 128)) * 128 + (row0 & 127);
            *reinterpret_cast<float4*>(Cf2 + bb) = make_float4(v[0], v[1], v[2], v[3]);
        } else {
            #pragma unroll
            for (int q = 0; q < 4; q++) {
                int row = row0 + q;
                float t = acc[rf][q];
                if (EPI == 2) {
                    t *= AUX[row];
                    unsigned short h, lo; splitbf(t, h, lo);
                    Ch[(size_t)row * 128 + colg] = h;
                    Cl[(size_t)row * 128 + colg] = lo;
                }
                if (EPI == 4) {
                    t += bias[colg];
                    t = fmaxf(t, 0.0f) + log1pf(expf(-fabsf(t)));
                    unsigned short h, lo; splitbf(t, h, lo);
                    Ch[(size_t)row * 128 + colg] = h;
                    Cl[(size_t)row * 128 + colg] = lo;
                }
                if (EPI == 5) {
                    t = isfinite(t) ? t : 0.0f;
                    t += AUX[(size_t)row * 128 + colg];
                    Cf[(size_t)row * cstride + colg] = t;
                }
                if (EPI == 6) {   // colg < 128 half
                    t += bias[colg];
                    Cf[(size_t)row * 128 + colg] = t;
                }
            }
        }
    }
}

// ---------------------------------------------------------------------------
// convsm_k: conv1d + silu -> xc planes [t][d] + xcT fp32 [b][d][t]; bcT [b][c][t]
__global__ __launch_bounds__(256) void convsm_k(const float* __restrict__ xm,
                                                const float* __restrict__ conv_w,
                                                const float* __restrict__ conv_b,
                                                const float* __restrict__ xpw,
                                                unsigned short* __restrict__ xch,
                                                unsigned short* __restrict__ xcl,
                                                float* __restrict__ xcT,
                                                float* __restrict__ bcT) {
    int tid = threadIdx.x;
    int slot = tid >> 7;
    int d = tid & 127;
    int ln = tid & 63;
    int wv = (tid >> 6) & 1;
    __shared__ float red[2][2][4];
    __shared__ float xcs[4][128];
    float cw[4];
    #pragma unroll
    for (int jj = 0; jj < 4; jj++) cw[jj] = conv_w[d * 4 + jj];
    float cb = conv_b[d];
    float4 wv4 = *reinterpret_cast<const float4*>(xpw + d * 12 + 8);

    #pragma unroll
    for (int it = 0; it < 2; it++) {
        int row = blockIdx.x * 4 + it * 2 + slot;
        int bt = row & 127;
        float accv = cb;
        #pragma unroll
        for (int jj = 0; jj < 4; jj++) {
            int tt = bt + jj - 3;
            if (tt >= 0) accv = fmaf(xm[((size_t)(row + jj - 3)) * 128 + d], cw[jj], accv);
        }
        float xcv = accv / (1.0f + expf(-accv));   // silu
        xcs[it * 2 + slot][d] = xcv;
        unsigned short h, lo; splitbf(xcv, h, lo);
        xch[(size_t)row * D_ + d] = h;
        xcl[(size_t)row * D_ + d] = lo;
        float p0 = xcv * wv4.x, p1 = xcv * wv4.y, p2 = xcv * wv4.z, p3 = xcv * wv4.w;
        #pragma unroll
        for (int o = 32; o > 0; o >>= 1) {
            p0 += __shfl_down(p0, o, 64);
            p1 += __shfl_down(p1, o, 64);
            p2 += __shfl_down(p2, o, 64);
            p3 += __shfl_down(p3, o, 64);
        }
        if (ln == 0) {
            red[slot][wv][0] = p0; red[slot][wv][1] = p1;
            red[slot][wv][2] = p2; red[slot][wv][3] = p3;
        }
        __syncthreads();
        if (d < 4) {
            int b = row >> 7;
            bcT[(size_t)b * 512 + d * 128 + (row & 127)] = red[slot][0][d] + red[slot][1][d];
        }
        __syncthreads();
    }
    // transpose-write xcT [b][d][t0..t0+3]
    if (tid < 128) {
        int b = blockIdx.x >> 5;
        int t0 = (blockIdx.x * 4) & 127;
        float4 v = make_float4(xcs[0][tid], xcs[1][tid], xcs[2][tid], xcs[3][tid]);
        *reinterpret_cast<float4*>(xcT + ((size_t)b * 128 + tid) * 128 + t0) = v;
    }
}

// ---------------------------------------------------------------------------
// scan_k: vectorized selective scan over t-contiguous feeds.
// grid 32 x 256; thread = (b, d).  Outputs y planes [t][d] (coalesced over d).
__global__ __launch_bounds__(256) void scan_k(const float* __restrict__ dpT,
                                              const float* __restrict__ xcT,
                                              const float* __restrict__ bcT,
                                              const float* __restrict__ resT,
                                              const float* __restrict__ A_log,
                                              const float* __restrict__ Dpar,
                                              unsigned short* __restrict__ yh,
                                              unsigned short* __restrict__ yl) {
    int g = blockIdx.x * 256 + threadIdx.x;
    int b = g >> 7, d = g & 127;
    float a1 = -expf(A_log[d * 2]);
    float a2 = -expf(A_log[d * 2 + 1]);
    float Dp = Dpar[d];
    const float4* dp4 = reinterpret_cast<const float4*>(dpT + ((size_t)b * 128 + d) * 128);
    const float4* xc4 = reinterpret_cast<const float4*>(xcT + ((size_t)b * 128 + d) * 128);
    const float4* rr4 = reinterpret_cast<const float4*>(resT + ((size_t)b * 128 + d) * 128);
    const float4* b04 = reinterpret_cast<const float4*>(bcT + (size_t)b * 512);
    const float4* b14 = b04 + 32;
    const float4* c04 = b04 + 64;
    const float4* c14 = b04 + 96;
    float h1 = 0.0f, h2 = 0.0f;
    size_t ybase = (size_t)b * 16384 + d;
    #pragma unroll 4
    for (int tc = 0; tc < 32; tc++) {
        float4 dp = dp4[tc], xc = xc4[tc], rr = rr4[tc];
        float4 bm0 = b04[tc], bm1 = b14[tc], cm0 = c04[tc], cm1 = c14[tc];
        #pragma unroll
        for (int q = 0; q < 4; q++) {
            float dpv = (q == 0) ? dp.x : (q == 1) ? dp.y : (q == 2) ? dp.z : dp.w;
            float xcv = (q == 0) ? xc.x : (q == 1) ? xc.y : (q == 2) ? xc.z : xc.w;
            float rv  = (q == 0) ? rr.x : (q == 1) ? rr.y : (q == 2) ? rr.z : rr.w;
            float bmv0 = (q == 0) ? bm0.x : (q == 1) ? bm0.y : (q == 2) ? bm0.z : bm0.w;
            float bmv1 = (q == 0) ? bm1.x : (q == 1) ? bm1.y : (q == 2) ? bm1.z : bm1.w;
            float cmv0 = (q == 0) ? cm0.x : (q == 1) ? cm0.y : (q == 2) ? cm0.z : cm0.w;
            float cmv1 = (q == 0) ? cm1.x : (q == 1) ? cm1.y : (q == 2) ? cm1.z : cm1.w;
            float e1 = expf(dpv * a1), e2 = expf(dpv * a2);
            float bu = dpv * xcv;
            h1 = fmaf(e1, h1, bu * bmv0);
            h2 = fmaf(e2, h2, bu * bmv1);
            float y = fmaf(h1, cmv0, h2 * cmv1);
            float yv = fmaf(xcv, Dp, y) * rv;
            unsigned short hh, ll; splitbf(yv, hh, ll);
            int t = tc * 4 + q;
            yh[ybase + (size_t)t * 128] = hh;
            yl[ybase + (size_t)t * 128] = ll;
        }
    }
}

// ---------------------------------------------------------------------------
extern "C" void kernel_launch(void* const* d_in, const int* in_sizes, int n_in,
                              void* d_out, int out_size, void* d_ws, size_t ws_size,
                              hipStream_t stream) {
    const float* x        = (const float*)d_in[0];
    const float* pos      = (const float*)d_in[1];
    const int*   mi       = (const int*)d_in[2];
    const float* norm_w   = (const float*)d_in[4];
    const float* w1       = (const float*)d_in[5];
    const float* b1       = (const float*)d_in[6];
    const float* w2       = (const float*)d_in[7];
    const float* b2       = (const float*)d_in[8];
    const float* lin_w    = (const float*)d_in[9];
    const float* lin_b    = (const float*)d_in[10];
    const float* in_proj  = (const float*)d_in[11];
    const float* conv_w   = (const float*)d_in[12];
    const float* conv_b   = (const float*)d_in[13];
    const float* xpw      = (const float*)d_in[14];
    const float* dtw      = (const float*)d_in[15];
    const float* dtb      = (const float*)d_in[16];
    const float* A_log    = (const float*)d_in[17];
    const float* Dpar     = (const float*)d_in[18];
    const float* out_proj = (const float*)d_in[19];

    float* out = (float*)d_out;
    char* base = (char*)d_ws;
    const size_t MB = 1u << 20;
    const size_t PL = 1048576;            // elements per bf16 plane

    float* x1f  = (float*)(base);                      // 4MB
    float* xm   = (float*)(base + 4 * MB);             // 4MB  fp32 [row][128]
    float* resT = (float*)(base + 8 * MB);             // 4MB  [b][d][t]
    float* dpT  = (float*)(base + 12 * MB);            // 4MB  [b][d][t]
    float* xcT  = (float*)(base + 16 * MB);            // 4MB  [b][d][t]
    float* bcT  = (float*)(base + 20 * MB);            // 128KB [b][4][t]
    float* rdeg = (float*)(base + 20 * MB + 131072);   // 32KB

    unsigned short* P = (unsigned short*)(base + 21 * MB);
    unsigned short* x1h  = P +  0 * PL;
    unsigned short* x1l  = P +  1 * PL;
    unsigned short* hTh  = P +  2 * PL;   // [b][n][k]
    unsigned short* hTl  = P +  3 * PL;
    unsigned short* aggh = P +  4 * PL;
    unsigned short* aggl = P +  5 * PL;
    unsigned short* xch  = P +  6 * PL;
    unsigned short* xcl  = P +  7 * PL;
    unsigned short* dlh  = P +  8 * PL;
    unsigned short* dll  = P +  9 * PL;
    unsigned short* yh   = P + 10 * PL;
    unsigned short* yl   = P + 11 * PL;
    unsigned short* adjh = P + 12 * PL;   // symmetric => also B^T
    unsigned short* adjl = P + 13 * PL;
    unsigned short* emh  = P + 14 * PL;

    unsigned short* W = (unsigned short*)(base + 52 * MB);
    unsigned short* w1Th = W;
    unsigned short* w1Tl = W + 16384;
    unsigned short* WdTh = W + 2 * 16384;
    unsigned short* WdTl = W + 3 * 16384;
    unsigned short* opTh = W + 4 * 16384;
    unsigned short* opTl = W + 5 * 16384;
    unsigned short* WfTh = W + 6 * 16384;          // [256][128]
    unsigned short* WfTl = WfTh + 32768;
    float* bfv = (float*)(WfTl + 32768);

    const size_t gsm = 49152;   // 48KB

    // 1. setup: weights + copy + rmsnorm + adjacency
    setup_k<<<3714, 256, 0, stream>>>(x, norm_w, pos, mi, lin_w, lin_b,
                                      w1, w2, b2, in_proj, xpw, dtw, out_proj,
                                      w1Th, w1Tl, WdTh, WdTl, opTh, opTl, WfTh, WfTl,
                                      bfv, x1f, x1h, x1l, adjh, adjl, emh, rdeg, out);
    // 2. h = relu(x1 @ w1 + b1) -> hT planes
    mgemm_k<1, true><<<dim3(256, 2), 256, gsm, stream>>>(
        x1h, x1l, w1Th, w1Tl, b1, nullptr, nullptr, hTh, hTl, nullptr, 128, 0);
    // 3. agg = (em @ h[b]) * rdeg -> planes
    mgemm_k<2, false><<<dim3(256, 2), 256, gsm, stream>>>(
        emh, emh, hTh, hTl, nullptr, rdeg, nullptr, aggh, aggl, nullptr, 128, 16384);
    // 4. xr = agg @ Wf + bf ; cols<128 -> xm fp32, cols>=128 -> resT silu transposed
    mgemm_k<6, true><<<dim3(256, 4), 256, gsm, stream>>>(
        aggh, aggl, WfTh, WfTl, bfv, nullptr, xm, nullptr, nullptr, resT, 128, 0);
    // 5. conv + silu -> xc planes + xcT + bcT
    convsm_k<<<2048, 256, 0, stream>>>(xm, conv_w, conv_b, xpw, xch, xcl, xcT, bcT);
    // 6. delta = softplus(xc @ Wd + dtb) -> planes
    mgemm_k<4, true><<<dim3(256, 2), 256, gsm, stream>>>(
        xch, xcl, WdTh, WdTl, dtb, nullptr, nullptr, dlh, dll, nullptr, 128, 0);
    // 7. dpT = (delta @ adj[b])^T  [b][d][t]
    mgemm_k<7, true><<<dim3(256, 2), 256, gsm, stream>>>(
        dlh, dll, adjh, adjl, nullptr, nullptr, dpT, nullptr, nullptr, nullptr, 128, 16384);
    // 8. scan -> y planes [t][d]
    scan_k<<<32, 256, 0, stream>>>(dpT, xcT, bcT, resT, A_log, Dpar, yh, yl);
    // 9. out = clean(y @ out_proj) + x1
    mgemm_k<5, true><<<dim3(256, 2), 256, gsm, stream>>>(
        yh, yl, opTh, opTl, nullptr, x1f, out, nullptr, nullptr, nullptr, 128, 0);
}

// Round 9
// 93.469 us; speedup vs baseline: 2.2094x; 1.0239x over previous
//
#include <hip/hip_runtime.h>
#include <math.h>

// Problem constants
#define B_ 64
#define N_ 128
#define D_ 128
#define BN_ 8192
#define NG_ 50
#define CUTOFF_ 10.0f

typedef __attribute__((ext_vector_type(8))) short short8v;   // 8 bf16
typedef __attribute__((ext_vector_type(4))) float f32x4;
#define MFMA16 __builtin_amdgcn_mfma_f32_16x16x32_bf16

__device__ __forceinline__ float bf2f(unsigned short h) {
    return __builtin_bit_cast(float, ((unsigned int)h) << 16);
}
__device__ __forceinline__ unsigned short f2bf(float f) {
    unsigned int u = __builtin_bit_cast(unsigned int, f);
    return (unsigned short)((u + 0x7FFFu + ((u >> 16) & 1u)) >> 16);
}
__device__ __forceinline__ void splitbf(float x, unsigned short& h, unsigned short& l) {
    h = f2bf(x);
    l = f2bf(x - bf2f(h));
}
__device__ __forceinline__ void gl_lds(const void* g, void* l) {
    __builtin_amdgcn_global_load_lds(
        (const __attribute__((address_space(1))) void*)g,
        (__attribute__((address_space(3))) void*)l, 16, 0, 0);
}

// ---------------------------------------------------------------------------
// setup_k: weight prep [0,513) | copy [513,642) | RMSNorm [642,2690) |
//          adjacency [2690,3714).  (round-8 proven, unchanged)
__global__ __launch_bounds__(256) void setup_k(
        const float* __restrict__ x, const float* __restrict__ norm_w,
        const float* __restrict__ pos, const int* __restrict__ mi,
        const float* __restrict__ lin_w, const float* __restrict__ lin_b,
        const float* __restrict__ w1, const float* __restrict__ w2,
        const float* __restrict__ b2, const float* __restrict__ in_proj,
        const float* __restrict__ xpw, const float* __restrict__ dtw,
        const float* __restrict__ out_proj,
        unsigned short* __restrict__ w1Th, unsigned short* __restrict__ w1Tl,
        unsigned short* __restrict__ WdTh, unsigned short* __restrict__ WdTl,
        unsigned short* __restrict__ opTh, unsigned short* __restrict__ opTl,
        unsigned short* __restrict__ WfTh, unsigned short* __restrict__ WfTl,
        float* __restrict__ bfv,
        float* __restrict__ x1f, unsigned short* __restrict__ x1h,
        unsigned short* __restrict__ x1l,
        unsigned short* __restrict__ adjh, unsigned short* __restrict__ adjl,
        unsigned short* __restrict__ emh, float* __restrict__ rdeg,
        float* __restrict__ out) {
    int blk = blockIdx.x, t = threadIdx.x;
    if (blk < 513) {
        if (blk < 128) {
            if (t < 128) {
                unsigned short h, l;
                splitbf(w1[blk * 128 + t], h, l);
                w1Th[t * 128 + blk] = h; w1Tl[t * 128 + blk] = l;
            }
        } else if (blk < 256) {
            int m = blk - 128;
            if (t < 128) {
                float s = 0.0f;
                #pragma unroll
                for (int r = 0; r < 8; r++) s = fmaf(xpw[m * 12 + r], dtw[r * 128 + t], s);
                unsigned short h, l; splitbf(s, h, l);
                WdTh[t * 128 + m] = h; WdTl[t * 128 + m] = l;
            }
        } else if (blk < 384) {
            int k = blk - 256;
            if (t < 128) {
                unsigned short h, l;
                splitbf(out_proj[k * 128 + t], h, l);
                opTh[t * 128 + k] = h; opTl[t * 128 + k] = l;
            }
        } else if (blk < 512) {
            int k = blk - 384;
            float s = 0.0f;
            #pragma unroll 8
            for (int j = 0; j < 128; j++) s = fmaf(w2[k * 128 + j], in_proj[j * 256 + t], s);
            unsigned short h, l; splitbf(s, h, l);
            WfTh[t * 128 + k] = h; WfTl[t * 128 + k] = l;
        } else {
            float s = 0.0f;
            #pragma unroll 8
            for (int j = 0; j < 128; j++) s = fmaf(b2[j], in_proj[j * 256 + t], s);
            bfv[t] = s;
        }
    } else if (blk < 642) {
        int idx = (blk - 513) * 256 + t;
        if (idx < BN_ * 3) out[(size_t)BN_ * D_ + idx] = pos[idx];
        if (idx < BN_) out[(size_t)BN_ * D_ + BN_ * 3 + idx] = (float)mi[idx];
    } else if (blk < 2690) {
        int rblk = blk - 642;
        int wv = t >> 6, ln = t & 63;
        int row = rblk * 4 + wv;
        const float2* xr = reinterpret_cast<const float2*>(x) + (size_t)row * 64;
        float2 v = xr[ln];
        float s = fmaf(v.x, v.x, v.y * v.y);
        #pragma unroll
        for (int o = 32; o > 0; o >>= 1) s += __shfl_down(s, o, 64);
        float tot = __shfl(s, 0, 64);
        float r = rsqrtf(tot * (1.0f / D_) + 1e-5f);
        float2 wv2 = reinterpret_cast<const float2*>(norm_w)[ln];
        float o0 = v.x * r * wv2.x, o1 = v.y * r * wv2.y;
        reinterpret_cast<float2*>(x1f)[(size_t)row * 64 + ln] = make_float2(o0, o1);
        unsigned short h0, l0, h1, l1;
        splitbf(o0, h0, l0); splitbf(o1, h1, l1);
        reinterpret_cast<ushort2*>(x1h)[(size_t)row * 64 + ln] = make_ushort2(h0, h1);
        reinterpret_cast<ushort2*>(x1l)[(size_t)row * 64 + ln] = make_ushort2(l0, l1);
    } else {
        __shared__ float px[N_], py[N_], pz[N_];
        __shared__ float lw[NG_];
        __shared__ int degs[8];
        int ablk = blk - 2690;
        int bx = ablk & 15, b = ablk >> 4;
        if (t < N_) {
            const float* p = pos + (size_t)(b * N_ + t) * 3;
            px[t] = p[0]; py[t] = p[1]; pz[t] = p[2];
        } else if (t - N_ < NG_) {
            lw[t - N_] = lin_w[t - N_];
        }
        if (t >= 248) degs[t - 248] = 0;
        __syncthreads();
        float linb = lin_b[0];
        int j = t & 127;
        int il = t >> 7;
        const float DEL = 10.0f / 49.0f;
        const float COEFF = -0.5f / (DEL * DEL);
        #pragma unroll
        for (int p = 0; p < 4; p++) {
            int i = bx * 8 + p * 2 + il;
            float dx = px[i] - px[j], dy = py[i] - py[j], dz = pz[i] - pz[j];
            float d2 = dx * dx + dy * dy + dz * dz;
            float dist = (i == j) ? 1.0f : sqrtf(d2);
            bool edge = (i != j) && (dist < CUTOFF_);
            float val = 0.0f;
            if (edge) {
                int g0 = (int)ceilf((dist - 1.75f) / DEL); if (g0 < 0) g0 = 0;
                int g1 = (int)floorf((dist + 1.75f) / DEL); if (g1 > NG_ - 1) g1 = NG_ - 1;
                float s = linb;
                for (int g = g0; g <= g1; g++) {
                    float tt = dist - (float)g * DEL;
                    s += lw[g] * expf(COEFF * tt * tt);
                }
                val = s;
            }
            size_t idx = ((size_t)b * N_ + i) * N_ + j;
            unsigned short h, l; splitbf(val, h, l);
            adjh[idx] = h; adjl[idx] = l;
            emh[idx] = edge ? 0x3F80 : 0;
            unsigned long long msk = __ballot(edge);
            if ((t & 63) == 0) atomicAdd(&degs[p * 2 + il], __popcll(msk));
        }
        __syncthreads();
        if (t < 8) {
            int dg = degs[t];
            rdeg[(size_t)b * N_ + bx * 8 + t] = 1.0f / (float)(dg > 0 ? dg : 1);
        }
    }
}

// ---------------------------------------------------------------------------
// Split-bf16 MFMA GEMM (round-5/8 proven).  32x64 tile, 4 waves, 48KB LDS.
// EPI: 1 relu+bias -> hT planes (batched) | 2 *AUX[row] -> planes |
//      5 isfinite + AUX residual -> fp32
#define AHOFF 0
#define ALOFF 8192
#define BHOFF 16384
#define BLOFF 32768
template <int EPI, bool ALO>
__global__ __launch_bounds__(256, 3) void mgemm_k(
        const unsigned short* __restrict__ Ah, const unsigned short* __restrict__ Al,
        const unsigned short* __restrict__ BTh, const unsigned short* __restrict__ BTl,
        const float* __restrict__ bias, const float* __restrict__ AUX,
        float* __restrict__ Cf, unsigned short* __restrict__ Ch,
        unsigned short* __restrict__ Cl, int cstride, int wbs) {
    extern __shared__ char sm[];
    int tid = threadIdx.x;
    int row_base = blockIdx.x * 32;
    int col_base = blockIdx.y * 64;

    const unsigned short* pBh = BTh;
    const unsigned short* pBl = BTl;
    if (wbs) {
        size_t bo = (size_t)(row_base >> 7) * (size_t)wbs;
        pBh += bo; pBl += bo;
    }

    #pragma unroll
    for (int i = 0; i < 2; i++) {
        int s = tid + i * 256;
        int row = s >> 4, inner = s & 15;
        int gb = (inner * 16) ^ ((row & 7) << 4);
        size_t gsrc = (size_t)(row_base + row) * 256 + gb;
        gl_lds((const char*)Ah + gsrc, sm + AHOFF + s * 16);
        if (ALO) gl_lds((const char*)Al + gsrc, sm + ALOFF + s * 16);
    }
    #pragma unroll
    for (int i = 0; i < 4; i++) {
        int s = tid + i * 256;
        int n = s >> 4, inner = s & 15;
        int gb = (inner * 16) ^ ((n & 7) << 4);
        size_t gsrc = (size_t)(col_base + n) * 256 + gb;
        gl_lds((const char*)pBh + gsrc, sm + BHOFF + s * 16);
        gl_lds((const char*)pBl + gsrc, sm + BLOFF + s * 16);
    }
    __syncthreads();

    int w = tid >> 6, l = tid & 63;
    int rlow = l & 15, kb_lane = (l >> 4) * 16;
    int nB = w * 16 + rlow;
    int nswz = (nB & 7) << 4;
    f32x4 acc[2] = {{0.f, 0.f, 0.f, 0.f}, {0.f, 0.f, 0.f, 0.f}};
    #pragma unroll
    for (int kb = 0; kb < 4; kb++) {
        int kbyte = kb * 64 + kb_lane;
        short8v bh = *(const short8v*)(sm + BHOFF + nB * 256 + (kbyte ^ nswz));
        short8v bl = *(const short8v*)(sm + BLOFF + nB * 256 + (kbyte ^ nswz));
        #pragma unroll
        for (int rf = 0; rf < 2; rf++) {
            int ra = rf * 16 + rlow;
            int aswz = (ra & 7) << 4;
            short8v ah = *(const short8v*)(sm + AHOFF + ra * 256 + (kbyte ^ aswz));
            acc[rf] = MFMA16(ah, bh, acc[rf], 0, 0, 0);
            acc[rf] = MFMA16(ah, bl, acc[rf], 0, 0, 0);
            if (ALO) {
                short8v al_ = *(const short8v*)(sm + ALOFF + ra * 256 + (kbyte ^ aswz));
                acc[rf] = MFMA16(al_, bh, acc[rf], 0, 0, 0);
            }
        }
    }

    int colg = col_base + w * 16 + rlow;
    #pragma unroll
    for (int rf = 0; rf < 2; rf++) {
        int row0 = row_base + rf * 16 + (l >> 4) * 4;
        if (EPI == 1) {
            float b_ = bias[colg];
            unsigned short hh[4], ll[4];
            #pragma unroll
            for (int q = 0; q < 4; q++) {
                float t = fmaxf(acc[rf][q] + b_, 0.0f);
                splitbf(t, hh[q], ll[q]);
            }
            size_t bb = (size_t)(row0 >> 7) * 16384 + (size_t)colg * 128 + (row0 & 127);
            *reinterpret_cast<ushort4*>(Ch + bb) = make_ushort4(hh[0], hh[1], hh[2], hh[3]);
            *reinterpret_cast<ushort4*>(Cl + bb) = make_ushort4(ll[0], ll[1], ll[2], ll[3]);
        } else {
            #pragma unroll
            for (int q = 0; q < 4; q++) {
                int row = row0 + q;
                float t = acc[rf][q];
                if (EPI == 2) {
                    t *= AUX[row];
                    unsigned short h, lo; splitbf(t, h, lo);
                    Ch[(size_t)row * 128 + colg] = h;
                    Cl[(size_t)row * 128 + colg] = lo;
                }
                if (EPI == 5) {
                    t = isfinite(t) ? t : 0.0f;
                    t += AUX[(size_t)row * 128 + colg];
                    Cf[(size_t)row * cstride + colg] = t;
                }
            }
        }
    }
}

// ---------------------------------------------------------------------------
// fused_k staging/GEMM helpers (512 threads)
__device__ __forceinline__ void st128(char* dst, const char* g, int tid) {
    #pragma unroll
    for (int i = 0; i < 4; i++) {
        int s = tid + i * 512;
        int row = s >> 4, inner = s & 15;
        gl_lds(g + row * 256 + ((inner * 16) ^ ((row & 7) << 4)), dst + s * 16);
    }
}
__device__ __forceinline__ void stA48(char* dst, const char* g, int r0, int tid) {
    #pragma unroll
    for (int i = 0; i < 2; i++) {
        int s = tid + i * 512;
        if (s < 768) {
            int lr = s >> 4, inner = s & 15;
            int srow = r0 - 16 + lr; if (srow < 0) srow = 0;
            gl_lds(g + srow * 256 + ((inner * 16) ^ ((lr & 7) << 4)), dst + s * 16);
        }
    }
}
template <int NRF>
__device__ __forceinline__ void fpass(const char* sm, int ah, int al, int bh, int bl,
                                      int w, int l, f32x4 (&acc)[NRF]) {
    int rlow = l & 15, khi = (l >> 4) * 16;
    int nB = w * 16 + rlow;
    int nkey = (nB & 7) << 4;
    #pragma unroll
    for (int kb = 0; kb < 4; kb++) {
        int kbyte = kb * 64 + khi;
        short8v bhv = *(const short8v*)(sm + bh + nB * 256 + (kbyte ^ nkey));
        short8v blv = *(const short8v*)(sm + bl + nB * 256 + (kbyte ^ nkey));
        #pragma unroll
        for (int rf = 0; rf < NRF; rf++) {
            int ra = rf * 16 + rlow;
            int ao = ra * 256 + (kbyte ^ ((ra & 7) << 4));
            short8v ahv = *(const short8v*)(sm + ah + ao);
            short8v alv = *(const short8v*)(sm + al + ao);
            acc[rf] = MFMA16(ahv, bhv, acc[rf], 0, 0, 0);
            acc[rf] = MFMA16(ahv, blv, acc[rf], 0, 0, 0);
            acc[rf] = MFMA16(alv, bhv, acc[rf], 0, 0, 0);
        }
    }
}

// ---------------------------------------------------------------------------
// fused_k: per (batch, 32-row group): xr GEMM (48 A-rows for conv look-back),
// conv1d+silu+bc, delta GEMM, dp GEMM.  grid 256 x 512, 160KB LDS.
__global__ __launch_bounds__(512, 2) void fused_k(
        const unsigned short* __restrict__ aggh, const unsigned short* __restrict__ aggl,
        const unsigned short* __restrict__ WfTh, const unsigned short* __restrict__ WfTl,
        const float* __restrict__ bfv,
        const float* __restrict__ conv_w, const float* __restrict__ conv_b,
        const float* __restrict__ xpw,
        const unsigned short* __restrict__ WdTh, const unsigned short* __restrict__ WdTl,
        const float* __restrict__ dtb,
        const unsigned short* __restrict__ adjh, const unsigned short* __restrict__ adjl,
        float* __restrict__ resT, float* __restrict__ xcT,
        float* __restrict__ bcT, float* __restrict__ dpT) {
    __shared__ __align__(16) char sm[163840];
    const int AH = 0, AL = 12288, XM = 24576, BH = 49152, BL = 81920,
              XCH = 114688, XCL = 122880, DH = 131072, DL = 139264, XCF = 147456;
    int blk = blockIdx.x, tid = threadIdx.x;
    int b = blk >> 2, r0 = (blk & 3) * 32;
    int w = tid >> 6, l = tid & 63;
    int rlow = l & 15, qrow = (l >> 4) * 4;

    // stage A (agg rows r0-16..r0+31, clamped) + B chunk 0 (Wf cols 0..127)
    stA48(sm + AH, (const char*)aggh + (size_t)b * 32768, r0, tid);
    stA48(sm + AL, (const char*)aggl + (size_t)b * 32768, r0, tid);
    st128(sm + BH, (const char*)WfTh, tid);
    st128(sm + BL, (const char*)WfTl, tid);
    __syncthreads();

    f32x4 acc[3] = {{0.f,0.f,0.f,0.f},{0.f,0.f,0.f,0.f},{0.f,0.f,0.f,0.f}};
    fpass<3>(sm, AH, AL, BH, BL, w, l, acc);
    __syncthreads();                         // chunk-0 B reads done
    st128(sm + BH, (const char*)WfTh + 32768, tid);   // n=128..255 (byte offset)
    st128(sm + BL, (const char*)WfTl + 32768, tid);
    // chunk-0 epilogue: xm -> XM (f32, swizzled)
    {
        int colg = w * 16 + rlow;
        float bb = bfv[colg];
        #pragma unroll
        for (int rf = 0; rf < 3; rf++) {
            #pragma unroll
            for (int q = 0; q < 4; q++) {
                int lr = rf * 16 + qrow + q;
                *(float*)(sm + XM + lr * 512 + ((colg * 4) ^ ((lr & 7) << 4))) =
                    acc[rf][q] + bb;
            }
        }
    }
    __syncthreads();                         // B1 staged; XM visible

    f32x4 acc2[3] = {{0.f,0.f,0.f,0.f},{0.f,0.f,0.f,0.f},{0.f,0.f,0.f,0.f}};
    fpass<3>(sm, AH, AL, BH, BL, w, l, acc2);
    // chunk-1 epilogue: res = silu -> resT [b][d][t]  (local rows 16..47 only)
    {
        int colg = w * 16 + rlow;
        float bb = bfv[128 + colg];
        #pragma unroll
        for (int rf = 1; rf < 3; rf++) {
            int lr0 = rf * 16 + qrow;
            int tt = r0 + lr0 - 16;
            float v[4];
            #pragma unroll
            for (int q = 0; q < 4; q++) {
                float rs = acc2[rf][q] + bb;
                v[q] = rs / (1.0f + expf(-rs));
            }
            *reinterpret_cast<float4*>(resT + ((size_t)b * 128 + colg) * 128 + tt) =
                make_float4(v[0], v[1], v[2], v[3]);
        }
    }
    __syncthreads();                         // chunk-1 B reads done; XM complete

    // stage Wd (overlaps conv) then conv1d + silu + bc
    st128(sm + BH, (const char*)WdTh, tid);
    st128(sm + BL, (const char*)WdTl, tid);
    {
        int ot = tid >> 4, dg = tid & 15;
        float pc0 = 0, pc1 = 0, pc2 = 0, pc3 = 0;
        #pragma unroll
        for (int k = 0; k < 8; k++) {
            int d = dg * 8 + k;
            float accv = conv_b[d];
            #pragma unroll
            for (int jj = 0; jj < 4; jj++) {
                int tt = r0 + ot + jj - 3;
                if (tt >= 0) {
                    int lr = ot + jj - 3 + 16;
                    float xv = *(const float*)(sm + XM + lr * 512 +
                                               ((d * 4) ^ ((lr & 7) << 4)));
                    accv = fmaf(xv, conv_w[d * 4 + jj], accv);
                }
            }
            float xc = accv / (1.0f + expf(-accv));   // silu
            unsigned short hh, ll; splitbf(xc, hh, ll);
            int pb = ot * 256 + ((d * 2) ^ ((ot & 7) << 4));
            *(unsigned short*)(sm + XCH + pb) = hh;
            *(unsigned short*)(sm + XCL + pb) = ll;
            *(float*)(sm + XCF + ot * 512 + ((d * 4) ^ ((ot & 7) << 4))) = xc;
            float4 xw = *(const float4*)(xpw + d * 12 + 8);
            pc0 = fmaf(xc, xw.x, pc0); pc1 = fmaf(xc, xw.y, pc1);
            pc2 = fmaf(xc, xw.z, pc2); pc3 = fmaf(xc, xw.w, pc3);
        }
        #pragma unroll
        for (int m = 1; m < 16; m <<= 1) {
            pc0 += __shfl_xor(pc0, m, 64);
            pc1 += __shfl_xor(pc1, m, 64);
            pc2 += __shfl_xor(pc2, m, 64);
            pc3 += __shfl_xor(pc3, m, 64);
        }
        if (dg < 4) {
            float pv = dg == 0 ? pc0 : dg == 1 ? pc1 : dg == 2 ? pc2 : pc3;
            bcT[(size_t)b * 512 + dg * 128 + r0 + ot] = pv;
        }
    }
    __syncthreads();                         // xc planes/XCF written; Wd staged

    // retranspose xc -> xcT [b][d][t]
    {
        int d = tid & 127, tg = tid >> 7;
        float v[8];
        #pragma unroll
        for (int k = 0; k < 8; k++) {
            int ot = tg * 8 + k;
            v[k] = *(const float*)(sm + XCF + ot * 512 + ((d * 4) ^ ((ot & 7) << 4)));
        }
        float* dst = xcT + ((size_t)b * 128 + d) * 128 + r0 + tg * 8;
        *reinterpret_cast<float4*>(dst) = make_float4(v[0], v[1], v[2], v[3]);
        *reinterpret_cast<float4*>(dst + 4) = make_float4(v[4], v[5], v[6], v[7]);
    }

    // delta = softplus(xc @ Wd + dtb) -> DH/DL planes
    f32x4 dacc[2] = {{0.f,0.f,0.f,0.f},{0.f,0.f,0.f,0.f}};
    fpass<2>(sm, XCH, XCL, BH, BL, w, l, dacc);
    {
        int colg = w * 16 + rlow;
        float db = dtb[colg];
        #pragma unroll
        for (int rf = 0; rf < 2; rf++) {
            #pragma unroll
            for (int q = 0; q < 4; q++) {
                int lr = rf * 16 + qrow + q;
                float t = dacc[rf][q] + db;
                t = fmaxf(t, 0.0f) + log1pf(expf(-fabsf(t)));
                unsigned short hh, ll; splitbf(t, hh, ll);
                int pb = lr * 256 + ((colg * 2) ^ ((lr & 7) << 4));
                *(unsigned short*)(sm + DH + pb) = hh;
                *(unsigned short*)(sm + DL + pb) = ll;
            }
        }
    }
    __syncthreads();                         // Wd reads done; DH/DL visible

    // dp = delta @ adj[b] -> dpT [b][d][t]
    st128(sm + BH, (const char*)adjh + (size_t)b * 32768, tid);
    st128(sm + BL, (const char*)adjl + (size_t)b * 32768, tid);
    __syncthreads();
    f32x4 pacc[2] = {{0.f,0.f,0.f,0.f},{0.f,0.f,0.f,0.f}};
    fpass<2>(sm, DH, DL, BH, BL, w, l, pacc);
    {
        int colg = w * 16 + rlow;
        #pragma unroll
        for (int rf = 0; rf < 2; rf++) {
            int lr0 = rf * 16 + qrow;
            *reinterpret_cast<float4*>(dpT + ((size_t)b * 128 + colg) * 128 + r0 + lr0) =
                make_float4(pacc[rf][0], pacc[rf][1], pacc[rf][2], pacc[rf][3]);
        }
    }
}

// ---------------------------------------------------------------------------
// scan_k: vectorized selective scan (round-8 proven, unchanged)
__global__ __launch_bounds__(256) void scan_k(const float* __restrict__ dpT,
                                              const float* __restrict__ xcT,
                                              const float* __restrict__ bcT,
                                              const float* __restrict__ resT,
                                              const float* __restrict__ A_log,
                                              const float* __restrict__ Dpar,
                                              unsigned short* __restrict__ yh,
                                              unsigned short* __restrict__ yl) {
    int g = blockIdx.x * 256 + threadIdx.x;
    int b = g >> 7, d = g & 127;
    float a1 = -expf(A_log[d * 2]);
    float a2 = -expf(A_log[d * 2 + 1]);
    float Dp = Dpar[d];
    const float4* dp4 = reinterpret_cast<const float4*>(dpT + ((size_t)b * 128 + d) * 128);
    const float4* xc4 = reinterpret_cast<const float4*>(xcT + ((size_t)b * 128 + d) * 128);
    const float4* rr4 = reinterpret_cast<const float4*>(resT + ((size_t)b * 128 + d) * 128);
    const float4* b04 = reinterpret_cast<const float4*>(bcT + (size_t)b * 512);
    const float4* b14 = b04 + 32;
    const float4* c04 = b04 + 64;
    const float4* c14 = b04 + 96;
    float h1 = 0.0f, h2 = 0.0f;
    size_t ybase = (size_t)b * 16384 + d;
    #pragma unroll 4
    for (int tc = 0; tc < 32; tc++) {
        float4 dp = dp4[tc], xc = xc4[tc], rr = rr4[tc];
        float4 bm0 = b04[tc], bm1 = b14[tc], cm0 = c04[tc], cm1 = c14[tc];
        #pragma unroll
        for (int q = 0; q < 4; q++) {
            float dpv = (q == 0) ? dp.x : (q == 1) ? dp.y : (q == 2) ? dp.z : dp.w;
            float xcv = (q == 0) ? xc.x : (q == 1) ? xc.y : (q == 2) ? xc.z : xc.w;
            float rv  = (q == 0) ? rr.x : (q == 1) ? rr.y : (q == 2) ? rr.z : rr.w;
            float bmv0 = (q == 0) ? bm0.x : (q == 1) ? bm0.y : (q == 2) ? bm0.z : bm0.w;
            float bmv1 = (q == 0) ? bm1.x : (q == 1) ? bm1.y : (q == 2) ? bm1.z : bm1.w;
            float cmv0 = (q == 0) ? cm0.x : (q == 1) ? cm0.y : (q == 2) ? cm0.z : cm0.w;
            float cmv1 = (q == 0) ? cm1.x : (q == 1) ? cm1.y : (q == 2) ? cm1.z : cm1.w;
            float e1 = expf(dpv * a1), e2 = expf(dpv * a2);
            float bu = dpv * xcv;
            h1 = fmaf(e1, h1, bu * bmv0);
            h2 = fmaf(e2, h2, bu * bmv1);
            float y = fmaf(h1, cmv0, h2 * cmv1);
            float yv = fmaf(xcv, Dp, y) * rv;
            unsigned short hh, ll; splitbf(yv, hh, ll);
            int t = tc * 4 + q;
            yh[ybase + (size_t)t * 128] = hh;
            yl[ybase + (size_t)t * 128] = ll;
        }
    }
}

// ---------------------------------------------------------------------------
extern "C" void kernel_launch(void* const* d_in, const int* in_sizes, int n_in,
                              void* d_out, int out_size, void* d_ws, size_t ws_size,
                              hipStream_t stream) {
    const float* x        = (const float*)d_in[0];
    const float* pos      = (const float*)d_in[1];
    const int*   mi       = (const int*)d_in[2];
    const float* norm_w   = (const float*)d_in[4];
    const float* w1       = (const float*)d_in[5];
    const float* b1       = (const float*)d_in[6];
    const float* w2       = (const float*)d_in[7];
    const float* b2       = (const float*)d_in[8];
    const float* lin_w    = (const float*)d_in[9];
    const float* lin_b    = (const float*)d_in[10];
    const float* in_proj  = (const float*)d_in[11];
    const float* conv_w   = (const float*)d_in[12];
    const float* conv_b   = (const float*)d_in[13];
    const float* xpw      = (const float*)d_in[14];
    const float* dtw      = (const float*)d_in[15];
    const float* dtb      = (const float*)d_in[16];
    const float* A_log    = (const float*)d_in[17];
    const float* Dpar     = (const float*)d_in[18];
    const float* out_proj = (const float*)d_in[19];

    float* out = (float*)d_out;
    char* base = (char*)d_ws;
    const size_t MB = 1u << 20;
    const size_t PL = 1048576;            // elements per bf16 plane

    float* x1f  = (float*)(base);                      // 4MB
    float* resT = (float*)(base + 8 * MB);             // 4MB  [b][d][t]
    float* dpT  = (float*)(base + 12 * MB);            // 4MB  [b][d][t]
    float* xcT  = (float*)(base + 16 * MB);            // 4MB  [b][d][t]
    float* bcT  = (float*)(base + 20 * MB);            // 128KB [b][4][t]
    float* rdeg = (float*)(base + 20 * MB + 131072);   // 32KB

    unsigned short* P = (unsigned short*)(base + 21 * MB);
    unsigned short* x1h  = P +  0 * PL;
    unsigned short* x1l  = P +  1 * PL;
    unsigned short* hTh  = P +  2 * PL;   // [b][n][k]
    unsigned short* hTl  = P +  3 * PL;
    unsigned short* aggh = P +  4 * PL;
    unsigned short* aggl = P +  5 * PL;
    unsigned short* yh   = P + 10 * PL;
    unsigned short* yl   = P + 11 * PL;
    unsigned short* adjh = P + 12 * PL;   // symmetric => also B^T
    unsigned short* adjl = P + 13 * PL;
    unsigned short* emh  = P + 14 * PL;

    unsigned short* W = (unsigned short*)(base + 52 * MB);
    unsigned short* w1Th = W;
    unsigned short* w1Tl = W + 16384;
    unsigned short* WdTh = W + 2 * 16384;
    unsigned short* WdTl = W + 3 * 16384;
    unsigned short* opTh = W + 4 * 16384;
    unsigned short* opTl = W + 5 * 16384;
    unsigned short* WfTh = W + 6 * 16384;          // [256][128]
    unsigned short* WfTl = WfTh + 32768;
    float* bfv = (float*)(WfTl + 32768);

    const size_t gsm = 49152;   // 48KB

    // 1. setup: weights + copy + rmsnorm + adjacency
    setup_k<<<3714, 256, 0, stream>>>(x, norm_w, pos, mi, lin_w, lin_b,
                                      w1, w2, b2, in_proj, xpw, dtw, out_proj,
                                      w1Th, w1Tl, WdTh, WdTl, opTh, opTl, WfTh, WfTl,
                                      bfv, x1f, x1h, x1l, adjh, adjl, emh, rdeg, out);
    // 2. h = relu(x1 @ w1 + b1) -> hT planes
    mgemm_k<1, true><<<dim3(256, 2), 256, gsm, stream>>>(
        x1h, x1l, w1Th, w1Tl, b1, nullptr, nullptr, hTh, hTl, 128, 0);
    // 3. agg = (em @ h[b]) * rdeg -> planes
    mgemm_k<2, false><<<dim3(256, 2), 256, gsm, stream>>>(
        emh, emh, hTh, hTl, nullptr, rdeg, nullptr, aggh, aggl, 128, 16384);
    // 4. fused middle: xr + conv/silu/bc + delta + dp
    fused_k<<<256, 512, 0, stream>>>(aggh, aggl, WfTh, WfTl, bfv,
                                     conv_w, conv_b, xpw, WdTh, WdTl, dtb,
                                     adjh, adjl, resT, xcT, bcT, dpT);
    // 5. scan -> y planes [t][d]
    scan_k<<<32, 256, 0, stream>>>(dpT, xcT, bcT, resT, A_log, Dpar, yh, yl);
    // 6. out = clean(y @ out_proj) + x1
    mgemm_k<5, true><<<dim3(256, 2), 256, gsm, stream>>>(
        yh, yl, opTh, opTl, nullptr, x1f, out, nullptr, nullptr, 128, 0);
}

// Round 10
// 91.206 us; speedup vs baseline: 2.2642x; 1.0248x over previous
//
#include <hip/hip_runtime.h>
#include <math.h>

// Problem constants
#define B_ 64
#define N_ 128
#define D_ 128
#define BN_ 8192
#define NG_ 50
#define CUTOFF_ 10.0f

typedef __attribute__((ext_vector_type(8))) short short8v;   // 8 bf16
typedef __attribute__((ext_vector_type(4))) float f32x4;
#define MFMA16 __builtin_amdgcn_mfma_f32_16x16x32_bf16

__device__ __forceinline__ float bf2f(unsigned short h) {
    return __builtin_bit_cast(float, ((unsigned int)h) << 16);
}
__device__ __forceinline__ unsigned short f2bf(float f) {
    unsigned int u = __builtin_bit_cast(unsigned int, f);
    return (unsigned short)((u + 0x7FFFu + ((u >> 16) & 1u)) >> 16);
}
__device__ __forceinline__ void splitbf(float x, unsigned short& h, unsigned short& l) {
    h = f2bf(x);
    l = f2bf(x - bf2f(h));
}
__device__ __forceinline__ void gl_lds(const void* g, void* l) {
    __builtin_amdgcn_global_load_lds(
        (const __attribute__((address_space(1))) void*)g,
        (__attribute__((address_space(3))) void*)l, 16, 0, 0);
}

// ---------------------------------------------------------------------------
// setup_k: weight prep [0,513) | copy [513,642) | RMSNorm [642,2690) |
//          adjacency [2690,3714).
__global__ __launch_bounds__(256) void setup_k(
        const float* __restrict__ x, const float* __restrict__ norm_w,
        const float* __restrict__ pos, const int* __restrict__ mi,
        const float* __restrict__ lin_w, const float* __restrict__ lin_b,
        const float* __restrict__ w1, const float* __restrict__ w2,
        const float* __restrict__ b2, const float* __restrict__ in_proj,
        const float* __restrict__ xpw, const float* __restrict__ dtw,
        const float* __restrict__ out_proj,
        unsigned short* __restrict__ w1Th, unsigned short* __restrict__ w1Tl,
        unsigned short* __restrict__ WdTh, unsigned short* __restrict__ WdTl,
        unsigned short* __restrict__ opTh, unsigned short* __restrict__ opTl,
        unsigned short* __restrict__ WfTh, unsigned short* __restrict__ WfTl,
        float* __restrict__ bfv,
        float* __restrict__ x1f, unsigned short* __restrict__ x1h,
        unsigned short* __restrict__ x1l,
        unsigned short* __restrict__ adjh, unsigned short* __restrict__ adjl,
        unsigned short* __restrict__ emh, float* __restrict__ rdeg,
        float* __restrict__ out) {
    int blk = blockIdx.x, t = threadIdx.x;
    if (blk < 513) {
        if (blk < 128) {
            if (t < 128) {
                unsigned short h, l;
                splitbf(w1[blk * 128 + t], h, l);
                w1Th[t * 128 + blk] = h; w1Tl[t * 128 + blk] = l;
            }
        } else if (blk < 256) {
            int m = blk - 128;
            if (t < 128) {
                float s = 0.0f;
                #pragma unroll
                for (int r = 0; r < 8; r++) s = fmaf(xpw[m * 12 + r], dtw[r * 128 + t], s);
                unsigned short h, l; splitbf(s, h, l);
                WdTh[t * 128 + m] = h; WdTl[t * 128 + m] = l;
            }
        } else if (blk < 384) {
            int k = blk - 256;
            if (t < 128) {
                unsigned short h, l;
                splitbf(out_proj[k * 128 + t], h, l);
                opTh[t * 128 + k] = h; opTl[t * 128 + k] = l;
            }
        } else if (blk < 512) {
            int k = blk - 384;
            float s = 0.0f;
            #pragma unroll 8
            for (int j = 0; j < 128; j++) s = fmaf(w2[k * 128 + j], in_proj[j * 256 + t], s);
            unsigned short h, l; splitbf(s, h, l);
            WfTh[t * 128 + k] = h; WfTl[t * 128 + k] = l;
        } else {
            float s = 0.0f;
            #pragma unroll 8
            for (int j = 0; j < 128; j++) s = fmaf(b2[j], in_proj[j * 256 + t], s);
            bfv[t] = s;
        }
    } else if (blk < 642) {
        int idx = (blk - 513) * 256 + t;
        if (idx < BN_ * 3) out[(size_t)BN_ * D_ + idx] = pos[idx];
        if (idx < BN_) out[(size_t)BN_ * D_ + BN_ * 3 + idx] = (float)mi[idx];
    } else if (blk < 2690) {
        int rblk = blk - 642;
        int wv = t >> 6, ln = t & 63;
        int row = rblk * 4 + wv;
        const float2* xr = reinterpret_cast<const float2*>(x) + (size_t)row * 64;
        float2 v = xr[ln];
        float s = fmaf(v.x, v.x, v.y * v.y);
        #pragma unroll
        for (int o = 32; o > 0; o >>= 1) s += __shfl_down(s, o, 64);
        float tot = __shfl(s, 0, 64);
        float r = rsqrtf(tot * (1.0f / D_) + 1e-5f);
        float2 wv2 = reinterpret_cast<const float2*>(norm_w)[ln];
        float o0 = v.x * r * wv2.x, o1 = v.y * r * wv2.y;
        reinterpret_cast<float2*>(x1f)[(size_t)row * 64 + ln] = make_float2(o0, o1);
        unsigned short h0, l0, h1, l1;
        splitbf(o0, h0, l0); splitbf(o1, h1, l1);
        reinterpret_cast<ushort2*>(x1h)[(size_t)row * 64 + ln] = make_ushort2(h0, h1);
        reinterpret_cast<ushort2*>(x1l)[(size_t)row * 64 + ln] = make_ushort2(l0, l1);
    } else {
        __shared__ float px[N_], py[N_], pz[N_];
        __shared__ float lw[NG_];
        __shared__ int degs[8];
        int ablk = blk - 2690;
        int bx = ablk & 15, b = ablk >> 4;
        if (t < N_) {
            const float* p = pos + (size_t)(b * N_ + t) * 3;
            px[t] = p[0]; py[t] = p[1]; pz[t] = p[2];
        } else if (t - N_ < NG_) {
            lw[t - N_] = lin_w[t - N_];
        }
        if (t >= 248) degs[t - 248] = 0;
        __syncthreads();
        float linb = lin_b[0];
        int j = t & 127;
        int il = t >> 7;
        const float DEL = 10.0f / 49.0f;
        const float COEFF = -0.5f / (DEL * DEL);
        #pragma unroll
        for (int p = 0; p < 4; p++) {
            int i = bx * 8 + p * 2 + il;
            float dx = px[i] - px[j], dy = py[i] - py[j], dz = pz[i] - pz[j];
            float d2 = dx * dx + dy * dy + dz * dz;
            float dist = (i == j) ? 1.0f : sqrtf(d2);
            bool edge = (i != j) && (dist < CUTOFF_);
            float val = 0.0f;
            if (edge) {
                int g0 = (int)ceilf((dist - 1.75f) / DEL); if (g0 < 0) g0 = 0;
                int g1 = (int)floorf((dist + 1.75f) / DEL); if (g1 > NG_ - 1) g1 = NG_ - 1;
                // Gaussian sum via 2-exp recurrence: t_{g+1}=t_g*u_g, u_{g+1}=u_g*e^-1
                // (2*COEFF*DEL^2 == -1 exactly). Truncated terms < 1e-16.
                float dm = dist - (float)g0 * DEL;
                float tg = expf(COEFF * dm * dm);
                float ug = expf(COEFF * DEL * (DEL - 2.0f * dm));
                float s = linb;
                for (int g = g0; g <= g1; g++) {
                    s = fmaf(lw[g], tg, s);
                    tg *= ug;
                    ug *= 0.36787944117144233f;   // e^{-1}
                }
                val = s;
            }
            size_t idx = ((size_t)b * N_ + i) * N_ + j;
            unsigned short h, l; splitbf(val, h, l);
            adjh[idx] = h; adjl[idx] = l;
            emh[idx] = edge ? 0x3F80 : 0;
            unsigned long long msk = __ballot(edge);
            if ((t & 63) == 0) atomicAdd(&degs[p * 2 + il], __popcll(msk));
        }
        __syncthreads();
        if (t < 8) {
            int dg = degs[t];
            rdeg[(size_t)b * N_ + bx * 8 + t] = 1.0f / (float)(dg > 0 ? dg : 1);
        }
    }
}

// ---------------------------------------------------------------------------
// Split-bf16 MFMA GEMM (proven).  32x64 tile, 4 waves, 48KB LDS.
// EPI: 1 relu+bias -> hT planes (batched) | 2 *AUX[row] -> planes |
//      5 isfinite + AUX residual -> fp32
#define AHOFF 0
#define ALOFF 8192
#define BHOFF 16384
#define BLOFF 32768
template <int EPI, bool ALO>
__global__ __launch_bounds__(256, 3) void mgemm_k(
        const unsigned short* __restrict__ Ah, const unsigned short* __restrict__ Al,
        const unsigned short* __restrict__ BTh, const unsigned short* __restrict__ BTl,
        const float* __restrict__ bias, const float* __restrict__ AUX,
        float* __restrict__ Cf, unsigned short* __restrict__ Ch,
        unsigned short* __restrict__ Cl, int cstride, int wbs) {
    extern __shared__ char sm[];
    int tid = threadIdx.x;
    int row_base = blockIdx.x * 32;
    int col_base = blockIdx.y * 64;

    const unsigned short* pBh = BTh;
    const unsigned short* pBl = BTl;
    if (wbs) {
        size_t bo = (size_t)(row_base >> 7) * (size_t)wbs;
        pBh += bo; pBl += bo;
    }

    #pragma unroll
    for (int i = 0; i < 2; i++) {
        int s = tid + i * 256;
        int row = s >> 4, inner = s & 15;
        int gb = (inner * 16) ^ ((row & 7) << 4);
        size_t gsrc = (size_t)(row_base + row) * 256 + gb;
        gl_lds((const char*)Ah + gsrc, sm + AHOFF + s * 16);
        if (ALO) gl_lds((const char*)Al + gsrc, sm + ALOFF + s * 16);
    }
    #pragma unroll
    for (int i = 0; i < 4; i++) {
        int s = tid + i * 256;
        int n = s >> 4, inner = s & 15;
        int gb = (inner * 16) ^ ((n & 7) << 4);
        size_t gsrc = (size_t)(col_base + n) * 256 + gb;
        gl_lds((const char*)pBh + gsrc, sm + BHOFF + s * 16);
        gl_lds((const char*)pBl + gsrc, sm + BLOFF + s * 16);
    }
    __syncthreads();

    int w = tid >> 6, l = tid & 63;
    int rlow = l & 15, kb_lane = (l >> 4) * 16;
    int nB = w * 16 + rlow;
    int nswz = (nB & 7) << 4;
    f32x4 acc[2] = {{0.f, 0.f, 0.f, 0.f}, {0.f, 0.f, 0.f, 0.f}};
    #pragma unroll
    for (int kb = 0; kb < 4; kb++) {
        int kbyte = kb * 64 + kb_lane;
        short8v bh = *(const short8v*)(sm + BHOFF + nB * 256 + (kbyte ^ nswz));
        short8v bl = *(const short8v*)(sm + BLOFF + nB * 256 + (kbyte ^ nswz));
        #pragma unroll
        for (int rf = 0; rf < 2; rf++) {
            int ra = rf * 16 + rlow;
            int aswz = (ra & 7) << 4;
            short8v ah = *(const short8v*)(sm + AHOFF + ra * 256 + (kbyte ^ aswz));
            acc[rf] = MFMA16(ah, bh, acc[rf], 0, 0, 0);
            acc[rf] = MFMA16(ah, bl, acc[rf], 0, 0, 0);
            if (ALO) {
                short8v al_ = *(const short8v*)(sm + ALOFF + ra * 256 + (kbyte ^ aswz));
                acc[rf] = MFMA16(al_, bh, acc[rf], 0, 0, 0);
            }
        }
    }

    int colg = col_base + w * 16 + rlow;
    #pragma unroll
    for (int rf = 0; rf < 2; rf++) {
        int row0 = row_base + rf * 16 + (l >> 4) * 4;
        if (EPI == 1) {
            float b_ = bias[colg];
            unsigned short hh[4], ll[4];
            #pragma unroll
            for (int q = 0; q < 4; q++) {
                float t = fmaxf(acc[rf][q] + b_, 0.0f);
                splitbf(t, hh[q], ll[q]);
            }
            size_t bb = (size_t)(row0 >> 7) * 16384 + (size_t)colg * 128 + (row0 & 127);
            *reinterpret_cast<ushort4*>(Ch + bb) = make_ushort4(hh[0], hh[1], hh[2], hh[3]);
            *reinterpret_cast<ushort4*>(Cl + bb) = make_ushort4(ll[0], ll[1], ll[2], ll[3]);
        } else {
            #pragma unroll
            for (int q = 0; q < 4; q++) {
                int row = row0 + q;
                float t = acc[rf][q];
                if (EPI == 2) {
                    t *= AUX[row];
                    unsigned short h, lo; splitbf(t, h, lo);
                    Ch[(size_t)row * 128 + colg] = h;
                    Cl[(size_t)row * 128 + colg] = lo;
                }
                if (EPI == 5) {
                    t = isfinite(t) ? t : 0.0f;
                    t += AUX[(size_t)row * 128 + colg];
                    Cf[(size_t)row * cstride + colg] = t;
                }
            }
        }
    }
}

// ---------------------------------------------------------------------------
// fused_k staging/GEMM helpers (512 threads)
__device__ __forceinline__ void st128(char* dst, const char* g, int tid) {
    #pragma unroll
    for (int i = 0; i < 4; i++) {
        int s = tid + i * 512;
        int row = s >> 4, inner = s & 15;
        gl_lds(g + row * 256 + ((inner * 16) ^ ((row & 7) << 4)), dst + s * 16);
    }
}
__device__ __forceinline__ void stA48(char* dst, const char* g, int r0, int tid) {
    #pragma unroll
    for (int i = 0; i < 2; i++) {
        int s = tid + i * 512;
        if (s < 768) {
            int lr = s >> 4, inner = s & 15;
            int srow = r0 - 16 + lr; if (srow < 0) srow = 0;
            gl_lds(g + srow * 256 + ((inner * 16) ^ ((lr & 7) << 4)), dst + s * 16);
        }
    }
}
template <int NRF>
__device__ __forceinline__ void fpass(const char* sm, int ah, int al, int bh, int bl,
                                      int w, int l, f32x4 (&acc)[NRF]) {
    int rlow = l & 15, khi = (l >> 4) * 16;
    int nB = w * 16 + rlow;
    int nkey = (nB & 7) << 4;
    #pragma unroll
    for (int kb = 0; kb < 4; kb++) {
        int kbyte = kb * 64 + khi;
        short8v bhv = *(const short8v*)(sm + bh + nB * 256 + (kbyte ^ nkey));
        short8v blv = *(const short8v*)(sm + bl + nB * 256 + (kbyte ^ nkey));
        #pragma unroll
        for (int rf = 0; rf < NRF; rf++) {
            int ra = rf * 16 + rlow;
            int ao = ra * 256 + (kbyte ^ ((ra & 7) << 4));
            short8v ahv = *(const short8v*)(sm + ah + ao);
            short8v alv = *(const short8v*)(sm + al + ao);
            acc[rf] = MFMA16(ahv, bhv, acc[rf], 0, 0, 0);
            acc[rf] = MFMA16(ahv, blv, acc[rf], 0, 0, 0);
            acc[rf] = MFMA16(alv, bhv, acc[rf], 0, 0, 0);
        }
    }
}

// ---------------------------------------------------------------------------
// fused_k: per (batch, 32-row group): xr GEMM (48 A-rows for conv look-back),
// conv1d+silu+bc, delta GEMM, dp GEMM.  grid 256 x 512, 160KB LDS.
__global__ __launch_bounds__(512, 2) void fused_k(
        const unsigned short* __restrict__ aggh, const unsigned short* __restrict__ aggl,
        const unsigned short* __restrict__ WfTh, const unsigned short* __restrict__ WfTl,
        const float* __restrict__ bfv,
        const float* __restrict__ conv_w, const float* __restrict__ conv_b,
        const float* __restrict__ xpw,
        const unsigned short* __restrict__ WdTh, const unsigned short* __restrict__ WdTl,
        const float* __restrict__ dtb,
        const unsigned short* __restrict__ adjh, const unsigned short* __restrict__ adjl,
        float* __restrict__ resT, float* __restrict__ xcT,
        float* __restrict__ bcT, float* __restrict__ dpT) {
    __shared__ __align__(16) char sm[163840];
    const int AH = 0, AL = 12288, XM = 24576, BH = 49152, BL = 81920,
              XCH = 114688, XCL = 122880, DH = 131072, DL = 139264, XCF = 147456;
    int blk = blockIdx.x, tid = threadIdx.x;
    int b = blk >> 2, r0 = (blk & 3) * 32;
    int w = tid >> 6, l = tid & 63;
    int rlow = l & 15, qrow = (l >> 4) * 4;

    stA48(sm + AH, (const char*)aggh + (size_t)b * 32768, r0, tid);
    stA48(sm + AL, (const char*)aggl + (size_t)b * 32768, r0, tid);
    st128(sm + BH, (const char*)WfTh, tid);
    st128(sm + BL, (const char*)WfTl, tid);
    __syncthreads();

    f32x4 acc[3] = {{0.f,0.f,0.f,0.f},{0.f,0.f,0.f,0.f},{0.f,0.f,0.f,0.f}};
    fpass<3>(sm, AH, AL, BH, BL, w, l, acc);
    __syncthreads();
    st128(sm + BH, (const char*)WfTh + 32768, tid);
    st128(sm + BL, (const char*)WfTl + 32768, tid);
    {
        int colg = w * 16 + rlow;
        float bb = bfv[colg];
        #pragma unroll
        for (int rf = 0; rf < 3; rf++) {
            #pragma unroll
            for (int q = 0; q < 4; q++) {
                int lr = rf * 16 + qrow + q;
                *(float*)(sm + XM + lr * 512 + ((colg * 4) ^ ((lr & 7) << 4))) =
                    acc[rf][q] + bb;
            }
        }
    }
    __syncthreads();

    f32x4 acc2[3] = {{0.f,0.f,0.f,0.f},{0.f,0.f,0.f,0.f},{0.f,0.f,0.f,0.f}};
    fpass<3>(sm, AH, AL, BH, BL, w, l, acc2);
    {
        int colg = w * 16 + rlow;
        float bb = bfv[128 + colg];
        #pragma unroll
        for (int rf = 1; rf < 3; rf++) {
            int lr0 = rf * 16 + qrow;
            int tt = r0 + lr0 - 16;
            float v[4];
            #pragma unroll
            for (int q = 0; q < 4; q++) {
                float rs = acc2[rf][q] + bb;
                v[q] = rs / (1.0f + expf(-rs));
            }
            *reinterpret_cast<float4*>(resT + ((size_t)b * 128 + colg) * 128 + tt) =
                make_float4(v[0], v[1], v[2], v[3]);
        }
    }
    __syncthreads();

    st128(sm + BH, (const char*)WdTh, tid);
    st128(sm + BL, (const char*)WdTl, tid);
    {
        int ot = tid >> 4, dg = tid & 15;
        float pc0 = 0, pc1 = 0, pc2 = 0, pc3 = 0;
        #pragma unroll
        for (int k = 0; k < 8; k++) {
            int d = dg * 8 + k;
            float accv = conv_b[d];
            #pragma unroll
            for (int jj = 0; jj < 4; jj++) {
                int tt = r0 + ot + jj - 3;
                if (tt >= 0) {
                    int lr = ot + jj - 3 + 16;
                    float xv = *(const float*)(sm + XM + lr * 512 +
                                               ((d * 4) ^ ((lr & 7) << 4)));
                    accv = fmaf(xv, conv_w[d * 4 + jj], accv);
                }
            }
            float xc = accv / (1.0f + expf(-accv));   // silu
            unsigned short hh, ll; splitbf(xc, hh, ll);
            int pb = ot * 256 + ((d * 2) ^ ((ot & 7) << 4));
            *(unsigned short*)(sm + XCH + pb) = hh;
            *(unsigned short*)(sm + XCL + pb) = ll;
            *(float*)(sm + XCF + ot * 512 + ((d * 4) ^ ((ot & 7) << 4))) = xc;
            float4 xw = *(const float4*)(xpw + d * 12 + 8);
            pc0 = fmaf(xc, xw.x, pc0); pc1 = fmaf(xc, xw.y, pc1);
            pc2 = fmaf(xc, xw.z, pc2); pc3 = fmaf(xc, xw.w, pc3);
        }
        #pragma unroll
        for (int m = 1; m < 16; m <<= 1) {
            pc0 += __shfl_xor(pc0, m, 64);
            pc1 += __shfl_xor(pc1, m, 64);
            pc2 += __shfl_xor(pc2, m, 64);
            pc3 += __shfl_xor(pc3, m, 64);
        }
        if (dg < 4) {
            float pv = dg == 0 ? pc0 : dg == 1 ? pc1 : dg == 2 ? pc2 : pc3;
            bcT[(size_t)b * 512 + dg * 128 + r0 + ot] = pv;
        }
    }
    __syncthreads();

    {
        int d = tid & 127, tg = tid >> 7;
        float v[8];
        #pragma unroll
        for (int k = 0; k < 8; k++) {
            int ot = tg * 8 + k;
            v[k] = *(const float*)(sm + XCF + ot * 512 + ((d * 4) ^ ((ot & 7) << 4)));
        }
        float* dst = xcT + ((size_t)b * 128 + d) * 128 + r0 + tg * 8;
        *reinterpret_cast<float4*>(dst) = make_float4(v[0], v[1], v[2], v[3]);
        *reinterpret_cast<float4*>(dst + 4) = make_float4(v[4], v[5], v[6], v[7]);
    }

    f32x4 dacc[2] = {{0.f,0.f,0.f,0.f},{0.f,0.f,0.f,0.f}};
    fpass<2>(sm, XCH, XCL, BH, BL, w, l, dacc);
    {
        int colg = w * 16 + rlow;
        float db = dtb[colg];
        #pragma unroll
        for (int rf = 0; rf < 2; rf++) {
            #pragma unroll
            for (int q = 0; q < 4; q++) {
                int lr = rf * 16 + qrow + q;
                float t = dacc[rf][q] + db;
                t = fmaxf(t, 0.0f) + log1pf(expf(-fabsf(t)));
                unsigned short hh, ll; splitbf(t, hh, ll);
                int pb = lr * 256 + ((colg * 2) ^ ((lr & 7) << 4));
                *(unsigned short*)(sm + DH + pb) = hh;
                *(unsigned short*)(sm + DL + pb) = ll;
            }
        }
    }
    __syncthreads();

    st128(sm + BH, (const char*)adjh + (size_t)b * 32768, tid);
    st128(sm + BL, (const char*)adjl + (size_t)b * 32768, tid);
    __syncthreads();
    f32x4 pacc[2] = {{0.f,0.f,0.f,0.f},{0.f,0.f,0.f,0.f}};
    fpass<2>(sm, DH, DL, BH, BL, w, l, pacc);
    {
        int colg = w * 16 + rlow;
        #pragma unroll
        for (int rf = 0; rf < 2; rf++) {
            int lr0 = rf * 16 + qrow;
            *reinterpret_cast<float4*>(dpT + ((size_t)b * 128 + colg) * 128 + r0 + lr0) =
                make_float4(pacc[rf][0], pacc[rf][1], pacc[rf][2], pacc[rf][3]);
        }
    }
}

// ---------------------------------------------------------------------------
// scan_k: state-split selective scan — 2 threads per (b,d), one per D_STATE
// channel; __shfl_xor combine.  grid 64 x 256.
__global__ __launch_bounds__(256) void scan_k(const float* __restrict__ dpT,
                                              const float* __restrict__ xcT,
                                              const float* __restrict__ bcT,
                                              const float* __restrict__ resT,
                                              const float* __restrict__ A_log,
                                              const float* __restrict__ Dpar,
                                              unsigned short* __restrict__ yh,
                                              unsigned short* __restrict__ yl) {
    int g = blockIdx.x * 256 + threadIdx.x;
    int b = g >> 8, rem = g & 255, d = rem >> 1, s = rem & 1;
    float a = -expf(A_log[d * 2 + s]);
    float Dp = Dpar[d];
    const float4* dp4 = reinterpret_cast<const float4*>(dpT + ((size_t)b * 128 + d) * 128);
    const float4* xc4 = reinterpret_cast<const float4*>(xcT + ((size_t)b * 128 + d) * 128);
    const float4* rr4 = reinterpret_cast<const float4*>(resT + ((size_t)b * 128 + d) * 128);
    const float4* bm4 = reinterpret_cast<const float4*>(bcT + (size_t)b * 512 + s * 128);
    const float4* cm4 = reinterpret_cast<const float4*>(bcT + (size_t)b * 512 + (2 + s) * 128);
    float h = 0.0f;
    size_t ybase = (size_t)b * 16384 + d;
    #pragma unroll 4
    for (int tc = 0; tc < 32; tc++) {
        float4 dp = dp4[tc], xc = xc4[tc], rr = rr4[tc];
        float4 bm = bm4[tc], cm = cm4[tc];
        #pragma unroll
        for (int q = 0; q < 4; q++) {
            float dpv = (q == 0) ? dp.x : (q == 1) ? dp.y : (q == 2) ? dp.z : dp.w;
            float xcv = (q == 0) ? xc.x : (q == 1) ? xc.y : (q == 2) ? xc.z : xc.w;
            float rv  = (q == 0) ? rr.x : (q == 1) ? rr.y : (q == 2) ? rr.z : rr.w;
            float bmv = (q == 0) ? bm.x : (q == 1) ? bm.y : (q == 2) ? bm.z : bm.w;
            float cmv = (q == 0) ? cm.x : (q == 1) ? cm.y : (q == 2) ? cm.z : cm.w;
            float e = expf(dpv * a);
            h = fmaf(e, h, dpv * xcv * bmv);
            float yc = h * cmv;
            float ysum = yc + __shfl_xor(yc, 1, 64);
            if (s == 0) {
                float yv = fmaf(xcv, Dp, ysum) * rv;
                unsigned short hh, ll; splitbf(yv, hh, ll);
                int t = tc * 4 + q;
                yh[ybase + (size_t)t * 128] = hh;
                yl[ybase + (size_t)t * 128] = ll;
            }
        }
    }
}

// ---------------------------------------------------------------------------
extern "C" void kernel_launch(void* const* d_in, const int* in_sizes, int n_in,
                              void* d_out, int out_size, void* d_ws, size_t ws_size,
                              hipStream_t stream) {
    const float* x        = (const float*)d_in[0];
    const float* pos      = (const float*)d_in[1];
    const int*   mi       = (const int*)d_in[2];
    const float* norm_w   = (const float*)d_in[4];
    const float* w1       = (const float*)d_in[5];
    const float* b1       = (const float*)d_in[6];
    const float* w2       = (const float*)d_in[7];
    const float* b2       = (const float*)d_in[8];
    const float* lin_w    = (const float*)d_in[9];
    const float* lin_b    = (const float*)d_in[10];
    const float* in_proj  = (const float*)d_in[11];
    const float* conv_w   = (const float*)d_in[12];
    const float* conv_b   = (const float*)d_in[13];
    const float* xpw      = (const float*)d_in[14];
    const float* dtw      = (const float*)d_in[15];
    const float* dtb      = (const float*)d_in[16];
    const float* A_log    = (const float*)d_in[17];
    const float* Dpar     = (const float*)d_in[18];
    const float* out_proj = (const float*)d_in[19];

    float* out = (float*)d_out;
    char* base = (char*)d_ws;
    const size_t MB = 1u << 20;
    const size_t PL = 1048576;            // elements per bf16 plane

    float* x1f  = (float*)(base);                      // 4MB
    float* resT = (float*)(base + 8 * MB);             // 4MB  [b][d][t]
    float* dpT  = (float*)(base + 12 * MB);            // 4MB  [b][d][t]
    float* xcT  = (float*)(base + 16 * MB);            // 4MB  [b][d][t]
    float* bcT  = (float*)(base + 20 * MB);            // 128KB [b][4][t]
    float* rdeg = (float*)(base + 20 * MB + 131072);   // 32KB

    unsigned short* P = (unsigned short*)(base + 21 * MB);
    unsigned short* x1h  = P +  0 * PL;
    unsigned short* x1l  = P +  1 * PL;
    unsigned short* hTh  = P +  2 * PL;   // [b][n][k]
    unsigned short* hTl  = P +  3 * PL;
    unsigned short* aggh = P +  4 * PL;
    unsigned short* aggl = P +  5 * PL;
    unsigned short* yh   = P + 10 * PL;
    unsigned short* yl   = P + 11 * PL;
    unsigned short* adjh = P + 12 * PL;   // symmetric => also B^T
    unsigned short* adjl = P + 13 * PL;
    unsigned short* emh  = P + 14 * PL;

    unsigned short* W = (unsigned short*)(base + 52 * MB);
    unsigned short* w1Th = W;
    unsigned short* w1Tl = W + 16384;
    unsigned short* WdTh = W + 2 * 16384;
    unsigned short* WdTl = W + 3 * 16384;
    unsigned short* opTh = W + 4 * 16384;
    unsigned short* opTl = W + 5 * 16384;
    unsigned short* WfTh = W + 6 * 16384;          // [256][128]
    unsigned short* WfTl = WfTh + 32768;
    float* bfv = (float*)(WfTl + 32768);

    const size_t gsm = 49152;   // 48KB

    // 1. setup: weights + copy + rmsnorm + adjacency
    setup_k<<<3714, 256, 0, stream>>>(x, norm_w, pos, mi, lin_w, lin_b,
                                      w1, w2, b2, in_proj, xpw, dtw, out_proj,
                                      w1Th, w1Tl, WdTh, WdTl, opTh, opTl, WfTh, WfTl,
                                      bfv, x1f, x1h, x1l, adjh, adjl, emh, rdeg, out);
    // 2. h = relu(x1 @ w1 + b1) -> hT planes
    mgemm_k<1, true><<<dim3(256, 2), 256, gsm, stream>>>(
        x1h, x1l, w1Th, w1Tl, b1, nullptr, nullptr, hTh, hTl, 128, 0);
    // 3. agg = (em @ h[b]) * rdeg -> planes
    mgemm_k<2, false><<<dim3(256, 2), 256, gsm, stream>>>(
        emh, emh, hTh, hTl, nullptr, rdeg, nullptr, aggh, aggl, 128, 16384);
    // 4. fused middle: xr + conv/silu/bc + delta + dp
    fused_k<<<256, 512, 0, stream>>>(aggh, aggl, WfTh, WfTl, bfv,
                                     conv_w, conv_b, xpw, WdTh, WdTl, dtb,
                                     adjh, adjl, resT, xcT, bcT, dpT);
    // 5. scan -> y planes [t][d]  (state-split, 64 blocks)
    scan_k<<<64, 256, 0, stream>>>(dpT, xcT, bcT, resT, A_log, Dpar, yh, yl);
    // 6. out = clean(y @ out_proj) + x1
    mgemm_k<5, true><<<dim3(256, 2), 256, gsm, stream>>>(
        yh, yl, opTh, opTl, nullptr, x1f, out, nullptr, nullptr, 128, 0);
}